// Round 3
// baseline (1524.199 us; speedup 1.0000x reference)
//
#include <hip/hip_runtime.h>
#include <hip/hip_bf16.h>
#include <stdint.h>

#define N_NODES 65536
#define N_EDGES (N_NODES * 16)
#define NEG_SLOPE 0.2f

typedef short bf16x8 __attribute__((ext_vector_type(8)));   // 8 bf16 in 4 VGPRs
typedef float f32x4 __attribute__((ext_vector_type(4)));
typedef unsigned int u32x2 __attribute__((ext_vector_type(2)));
typedef unsigned int u32x4 __attribute__((ext_vector_type(4)));

__device__ __forceinline__ unsigned short f2bf(float f) {
    unsigned u = __float_as_uint(f);
    u += 0x7fffu + ((u >> 16) & 1u);       // RNE
    return (unsigned short)(u >> 16);
}
__device__ __forceinline__ float bf2f(unsigned short h) {
    return __uint_as_float(((unsigned)h) << 16);
}
__device__ __forceinline__ void load_lds16(const void* g, void* l) {
    __builtin_amdgcn_global_load_lds(
        (const __attribute__((address_space(1))) unsigned int*)g,
        (__attribute__((address_space(3))) unsigned int*)l, 16, 0, 0);
}
// nontemporal 8B store of a ushort4 (streaming output; keep L2 for gather rows)
__device__ __forceinline__ void nt_store_us4(unsigned short* p, ushort4 v) {
    u32x2 d;
    d.x = (unsigned)v.x | ((unsigned)v.y << 16);
    d.y = (unsigned)v.z | ((unsigned)v.w << 16);
    __builtin_nontemporal_store(d, (u32x2*)p);
}

// ---------------- MFMA GEMM: C[M,Nw] = A[M,Kp] @ Wt^T (+bias,+relu) ----------------
// A: fp32 (A32 path, converted during staging) or bf16 hi/lo pair.
// Wt transposed [n][Kp] bf16 hi/lo, zero-padded.
// Split-bf16: acc += Ahi*Bhi + Alo*Bhi + Ahi*Blo  (fp32 MFMA accumulate).
// Block 256 = 4 waves; tile 128(M) x TN(N), TN in {64,128}; BK=32.
// If asrc != null: also computes per-row attention dots al_s/al_d (atomicAdd).
// slab8: C32 written as 8-col slabs [col/8][N_NODES][8] (contiguous 2MB slabs
// so the gather's per-XCD slice is L2-resident with zero cache-line waste).
template<int TN>
__global__ __launch_bounds__(256) void gemm_mfma(
    const float* __restrict__ A32, int KA,
    const unsigned short* __restrict__ Ahi, const unsigned short* __restrict__ Alo,
    int lda, int Kp,
    const unsigned short* __restrict__ Bhi, const unsigned short* __restrict__ Blo,
    const float* __restrict__ bias, int Nbias,
    float* __restrict__ C32,
    unsigned short* __restrict__ Chi, unsigned short* __restrict__ Clo,
    int ldc, int Nw, int relu, int slab8,
    const float* __restrict__ asrc, const float* __restrict__ adst,
    float* __restrict__ alS, float* __restrict__ alD, int Cal, int HCal)
{
    constexpr int NI = TN / 32;                 // N-frags per wave
    __shared__ unsigned short sAhi[128 * 32], sAlo[128 * 32];
    __shared__ unsigned short sBhi[TN * 32],  sBlo[TN * 32];
    __shared__ float sAl[128][2][4];
    const int tid = threadIdx.x;
    const int wave = tid >> 6, lane = tid & 63;
    const int row0 = blockIdx.y * 128;
    const int col0 = blockIdx.x * TN;
    const int wm = (wave & 1) * 64, wn = (wave >> 1) * (TN / 2);
    const int mlane = lane & 15, q = lane >> 4;

    f32x4 acc[4][NI];
#pragma unroll
    for (int a = 0; a < 4; ++a)
#pragma unroll
        for (int b = 0; b < NI; ++b) acc[a][b] = (f32x4){0.f, 0.f, 0.f, 0.f};

    for (int k0 = 0; k0 < Kp; k0 += 32) {
        __syncthreads();
        if (A32) {
            // fp32 -> bf16 hi/lo conversion staging (layer 1 only)
            const int r = tid >> 1, cbase = (tid & 1) * 16;
            const float* Ap = A32 + (size_t)(row0 + r) * lda;
#pragma unroll
            for (int j = 0; j < 4; ++j) {
                int kc = k0 + cbase + j * 4;
                float4 v = make_float4(0.f, 0.f, 0.f, 0.f);
                if (kc < KA) v = *(const float4*)(Ap + kc);
                ushort4 h, l;
                h.x = f2bf(v.x); l.x = f2bf(v.x - bf2f(h.x));
                h.y = f2bf(v.y); l.y = f2bf(v.y - bf2f(h.y));
                h.z = f2bf(v.z); l.z = f2bf(v.z - bf2f(h.z));
                h.w = f2bf(v.w); l.w = f2bf(v.w - bf2f(h.w));
                *(ushort4*)(sAhi + r * 32 + cbase + j * 4) = h;
                *(ushort4*)(sAlo + r * 32 + cbase + j * 4) = l;
            }
        } else {
            // async global->LDS, 16B/lane; LDS dst = wave-uniform base + lane*16
#pragma unroll
            for (int cc = 0; cc < 2; ++cc) {
                int c = wave * 2 + cc;                 // 8 chunks of 16 rows
                int r = c * 16 + (lane >> 2);
                size_t goff = (size_t)(row0 + r) * lda + k0 + (lane & 3) * 8;
                load_lds16(Ahi + goff, sAhi + c * 512);
                load_lds16(Alo + goff, sAlo + c * 512);
            }
        }
        {
#pragma unroll
            for (int cc = 0; cc < TN / 64; ++cc) {
                int c = wave * (TN / 64) + cc;         // TN/16 chunks of 16 rows
                int r = c * 16 + (lane >> 2);
                size_t goff = (size_t)(col0 + r) * Kp + k0 + (lane & 3) * 8;
                load_lds16(Bhi + goff, sBhi + c * 512);
                load_lds16(Blo + goff, sBlo + c * 512);
            }
        }
        __syncthreads();

        bf16x8 ah[4], al[4], bh[NI], bl[NI];
#pragma unroll
        for (int mi = 0; mi < 4; ++mi) {
            int m = wm + mi * 16 + mlane;
            ah[mi] = *(const bf16x8*)(sAhi + m * 32 + q * 8);
            al[mi] = *(const bf16x8*)(sAlo + m * 32 + q * 8);
        }
#pragma unroll
        for (int ni = 0; ni < NI; ++ni) {
            int n = wn + ni * 16 + mlane;
            bh[ni] = *(const bf16x8*)(sBhi + n * 32 + q * 8);
            bl[ni] = *(const bf16x8*)(sBlo + n * 32 + q * 8);
        }
#pragma unroll
        for (int mi = 0; mi < 4; ++mi)
#pragma unroll
            for (int ni = 0; ni < NI; ++ni) {
                acc[mi][ni] = __builtin_amdgcn_mfma_f32_16x16x32_bf16(ah[mi], bh[ni], acc[mi][ni], 0, 0, 0);
                acc[mi][ni] = __builtin_amdgcn_mfma_f32_16x16x32_bf16(al[mi], bh[ni], acc[mi][ni], 0, 0, 0);
                acc[mi][ni] = __builtin_amdgcn_mfma_f32_16x16x32_bf16(ah[mi], bl[ni], acc[mi][ni], 0, 0, 0);
            }
    }

    // epilogue: C/D frag layout col=lane&15, row=(lane>>4)*4+reg
#pragma unroll
    for (int ni = 0; ni < NI; ++ni) {
        int col = col0 + wn + ni * 16 + mlane;
        if (col >= Nw) continue;
        float bv = (bias && col < Nbias) ? bias[col] : 0.f;
#pragma unroll
        for (int mi = 0; mi < 4; ++mi) {
#pragma unroll
            for (int reg = 0; reg < 4; ++reg) {
                int row = row0 + wm + mi * 16 + q * 4 + reg;
                float v = acc[mi][ni][reg] + bv;
                if (relu) v = fmaxf(v, 0.f);
                if (Chi) {
                    size_t off = (size_t)row * ldc + col;
                    unsigned short h = f2bf(v);
                    Chi[off] = h;
                    Clo[off] = f2bf(v - bf2f(h));
                } else if (slab8) {
                    size_t off = ((size_t)(col >> 3) * N_NODES + row) * 8 + (col & 7);
                    C32[off] = v;
                } else {
                    C32[(size_t)row * ldc + col] = v;
                }
            }
        }
    }

    // fused attention-logit dots: al_s[row,h] += sum_c h[row,c]*a_s[h,c], same for a_d
    if (asrc) {
        float asv[NI], adv[NI];
        bool head0[NI];
#pragma unroll
        for (int ni = 0; ni < NI; ++ni) {
            int col = col0 + wn + ni * 16 + mlane;
            bool valid = col < HCal;
            head0[ni] = col < Cal;
            asv[ni] = valid ? asrc[col] : 0.f;
            adv[ni] = valid ? adst[col] : 0.f;
        }
#pragma unroll
        for (int mi = 0; mi < 4; ++mi) {
#pragma unroll
            for (int reg = 0; reg < 4; ++reg) {
                float s0 = 0.f, s1 = 0.f, d0 = 0.f, d1 = 0.f;
#pragma unroll
                for (int ni = 0; ni < NI; ++ni) {
                    float v = acc[mi][ni][reg];
                    if (head0[ni]) { s0 += v * asv[ni]; d0 += v * adv[ni]; }
                    else           { s1 += v * asv[ni]; d1 += v * adv[ni]; }
                }
#pragma unroll
                for (int off = 1; off < 16; off <<= 1) {
                    s0 += __shfl_xor(s0, off); s1 += __shfl_xor(s1, off);
                    d0 += __shfl_xor(d0, off); d1 += __shfl_xor(d1, off);
                }
                if (mlane == 0) {
                    int rl = wm + mi * 16 + q * 4 + reg;
                    int slot = wave >> 1;
                    sAl[rl][slot][0] = s0; sAl[rl][slot][1] = s1;
                    sAl[rl][slot][2] = d0; sAl[rl][slot][3] = d1;
                }
            }
        }
        __syncthreads();
        if (tid < 128) {
            int row = row0 + tid;
            float v0 = sAl[tid][0][0] + sAl[tid][1][0];
            float v1 = sAl[tid][0][1] + sAl[tid][1][1];
            float v2 = sAl[tid][0][2] + sAl[tid][1][2];
            float v3 = sAl[tid][0][3] + sAl[tid][1][3];
            atomicAdd(&alS[row * 2 + 0], v0);
            atomicAdd(&alS[row * 2 + 1], v1);
            atomicAdd(&alD[row * 2 + 0], v2);
            atomicAdd(&alD[row * 2 + 1], v3);
        }
    }
}

// ------------- fused MLP head: 4 layers in one kernel, 32 rows/block -------------
template<int NI>
__device__ __forceinline__ void mlp_layer(
    const unsigned short* aHi, const unsigned short* aLo, int ldaS, int K,
    const unsigned short* __restrict__ Bhi, const unsigned short* __restrict__ Blo,
    int Kp,
    unsigned short* sBh, unsigned short* sBl,
    const float* __restrict__ bias, int Nbias, int colBase,
    unsigned short* oHi, unsigned short* oLo, int ldo, int Nstore,
    float* __restrict__ gOut, int row0, int relu,
    int wave, int lane)
{
    const int mlane = lane & 15, q = lane >> 4;
    const int wm = (wave & 1) * 16;
    const int wn = (wave >> 1) * (NI * 16);
    f32x4 acc[NI];
#pragma unroll
    for (int b = 0; b < NI; ++b) acc[b] = (f32x4){0.f, 0.f, 0.f, 0.f};

    for (int k0 = 0; k0 < K; k0 += 32) {
        __syncthreads();
        for (int c = wave; c < NI * 2; c += 4) {   // stage B rows (N = NI*32)
            int r = c * 16 + (lane >> 2);
            size_t goff = (size_t)r * Kp + k0 + (lane & 3) * 8;
            load_lds16(Bhi + goff, sBh + c * 512);
            load_lds16(Blo + goff, sBl + c * 512);
        }
        __syncthreads();

        bf16x8 ah, al, bh[NI], bl[NI];
        ah = *(const bf16x8*)(aHi + (wm + mlane) * ldaS + k0 + q * 8);
        al = *(const bf16x8*)(aLo + (wm + mlane) * ldaS + k0 + q * 8);
#pragma unroll
        for (int ni = 0; ni < NI; ++ni) {
            int n = wn + ni * 16 + mlane;
            bh[ni] = *(const bf16x8*)(sBh + n * 32 + q * 8);
            bl[ni] = *(const bf16x8*)(sBl + n * 32 + q * 8);
        }
#pragma unroll
        for (int ni = 0; ni < NI; ++ni) {
            acc[ni] = __builtin_amdgcn_mfma_f32_16x16x32_bf16(ah, bh[ni], acc[ni], 0, 0, 0);
            acc[ni] = __builtin_amdgcn_mfma_f32_16x16x32_bf16(al, bh[ni], acc[ni], 0, 0, 0);
            acc[ni] = __builtin_amdgcn_mfma_f32_16x16x32_bf16(ah, bl[ni], acc[ni], 0, 0, 0);
        }
    }
    __syncthreads();   // all reads of aHi/aLo done before caller overwrites

#pragma unroll
    for (int ni = 0; ni < NI; ++ni) {
        int colg = colBase + wn + ni * 16 + mlane;
        float bv = (colg < Nbias) ? bias[colg] : 0.f;
#pragma unroll
        for (int reg = 0; reg < 4; ++reg) {
            int row = wm + q * 4 + reg;
            float v = acc[ni][reg] + bv;
            if (relu) v = fmaxf(v, 0.f);
            if (gOut) {
                if (colg < 29) gOut[(size_t)(row0 + row) * 29 + colg] = v;
            } else if (colg < Nstore) {
                unsigned short h = f2bf(v);
                oHi[row * ldo + colg] = h;
                oLo[row * ldo + colg] = f2bf(v - bf2f(h));
            }
        }
    }
}

__global__ __launch_bounds__(256) void mlp_fused(
    const unsigned short* __restrict__ actHi, const unsigned short* __restrict__ actLo,
    const unsigned short* __restrict__ L1h, const unsigned short* __restrict__ L1l,
    const unsigned short* __restrict__ L2h, const unsigned short* __restrict__ L2l,
    const unsigned short* __restrict__ L3h, const unsigned short* __restrict__ L3l,
    const unsigned short* __restrict__ L4h, const unsigned short* __restrict__ L4l,
    const float* __restrict__ B1, const float* __restrict__ B2,
    const float* __restrict__ B3, const float* __restrict__ B4,
    float* __restrict__ out)
{
    __shared__ unsigned short b1h[32 * 224], b1l[32 * 224];   // L1 out / L3 out
    __shared__ unsigned short b2h[32 * 128], b2l[32 * 128];   // L2 out
    __shared__ unsigned short sAh[32 * 32],  sAl[32 * 32];    // L1 A staging
    __shared__ unsigned short sBh[128 * 32], sBl[128 * 32];   // B staging
    const int tid = threadIdx.x;
    const int wave = tid >> 6, lane = tid & 63;
    const int row0 = blockIdx.x * 32;
    const int mlane = lane & 15, q = lane >> 4;
    const int wm = (wave & 1) * 16;
    const int wn = (wave >> 1) * 64;

    // ---- layer 1: [32,512] @ L1^T -> b1 [32,224], two 128-col tiles ----
    for (int nt = 0; nt < 2; ++nt) {
        const unsigned short* Bh = L1h + (size_t)nt * 128 * 512;
        const unsigned short* Bl = L1l + (size_t)nt * 128 * 512;
        f32x4 acc[4];
#pragma unroll
        for (int b = 0; b < 4; ++b) acc[b] = (f32x4){0.f, 0.f, 0.f, 0.f};
        for (int k0 = 0; k0 < 512; k0 += 32) {
            __syncthreads();
            for (int c = wave; c < 2; c += 4) {      // A: 32 rows
                int r = c * 16 + (lane >> 2);
                size_t goff = (size_t)(row0 + r) * 512 + k0 + (lane & 3) * 8;
                load_lds16(actHi + goff, sAh + c * 512);
                load_lds16(actLo + goff, sAl + c * 512);
            }
            for (int c = wave; c < 8; c += 4) {      // B: 128 rows
                int r = c * 16 + (lane >> 2);
                size_t goff = (size_t)r * 512 + k0 + (lane & 3) * 8;
                load_lds16(Bh + goff, sBh + c * 512);
                load_lds16(Bl + goff, sBl + c * 512);
            }
            __syncthreads();
            bf16x8 ah = *(const bf16x8*)(sAh + (wm + mlane) * 32 + q * 8);
            bf16x8 al = *(const bf16x8*)(sAl + (wm + mlane) * 32 + q * 8);
#pragma unroll
            for (int ni = 0; ni < 4; ++ni) {
                int n = wn + ni * 16 + mlane;
                bf16x8 bh = *(const bf16x8*)(sBh + n * 32 + q * 8);
                bf16x8 bl = *(const bf16x8*)(sBl + n * 32 + q * 8);
                acc[ni] = __builtin_amdgcn_mfma_f32_16x16x32_bf16(ah, bh, acc[ni], 0, 0, 0);
                acc[ni] = __builtin_amdgcn_mfma_f32_16x16x32_bf16(al, bh, acc[ni], 0, 0, 0);
                acc[ni] = __builtin_amdgcn_mfma_f32_16x16x32_bf16(ah, bl, acc[ni], 0, 0, 0);
            }
        }
        __syncthreads();
#pragma unroll
        for (int ni = 0; ni < 4; ++ni) {
            int colg = nt * 128 + wn + ni * 16 + mlane;
            float bv = (colg < 200) ? B1[colg] : 0.f;
#pragma unroll
            for (int reg = 0; reg < 4; ++reg) {
                int row = wm + q * 4 + reg;
                float v = fmaxf(acc[ni][reg] + bv, 0.f);
                if (colg < 224) {
                    unsigned short h = f2bf(v);
                    b1h[row * 224 + colg] = h;
                    b1l[row * 224 + colg] = f2bf(v - bf2f(h));
                }
            }
        }
    }
    __syncthreads();

    // ---- layer 2: b1[32,224] -> b2[32,128] ----
    mlp_layer<4>(b1h, b1l, 224, 224, L2h, L2l, 224, sBh, sBl,
                 B2, 100, 0, b2h, b2l, 128, 128, nullptr, 0, 1, wave, lane);
    __syncthreads();
    // ---- layer 3: b2[32,128] -> b1[32,128] (reuse, ld 128) ----
    mlp_layer<4>(b2h, b2l, 128, 128, L3h, L3l, 128, sBh, sBl,
                 B3, 100, 0, b1h, b1l, 128, 128, nullptr, 0, 1, wave, lane);
    __syncthreads();
    // ---- layer 4: b1[32,128] -> out[32,29] fp32 ----
    mlp_layer<2>(b1h, b1l, 128, 128, L4h, L4l, 128, sBh, sBl,
                 B4, 29, 0, nullptr, nullptr, 0, 0, out, row0, 0, wave, lane);
}

// ---------------- weight transpose + bf16 hi/lo decompose (all 8 in one) ----------
struct WtJob {
    const float* W; unsigned short* Whi; unsigned short* Wlo;
    int K, N, Kp, remap, nb0;
};
struct WtJobs { WtJob j[8]; };

__global__ void wt_decomp_all(WtJobs jobs)
{
    int b = blockIdx.x;
    int idx = 0;
#pragma unroll
    for (int i = 1; i < 8; ++i)
        if (b >= jobs.j[i].nb0) idx = i;
    WtJob jb = jobs.j[idx];
    int n = b - jb.nb0;
    for (int k = threadIdx.x; k < jb.Kp; k += 256) {
        int ks = k, valid = 1;
        if (jb.remap) {
            int bb = k >> 6, r = k & 63;
            if (r < 60) ks = bb * 60 + r; else valid = 0;
        }
        float v = 0.f;
        if (valid && ks < jb.K && n < jb.N) v = jb.W[(size_t)ks * jb.N + n];
        unsigned short h = f2bf(v);
        jb.Whi[(size_t)n * jb.Kp + k] = h;
        jb.Wlo[(size_t)n * jb.Kp + k] = f2bf(v - bf2f(h));
    }
}

// ------- per-node softmax stats (m, 1/den) for L1 sliced gather -------
// Identical FP sequence (strided-lane online update + butterfly) to the
// stats phase of gat_gather_fused -> bitwise-equal weights downstream.
__global__ __launch_bounds__(256) void attn_stats(
    const float* __restrict__ al_s, const float* __restrict__ al_d,
    const int* __restrict__ indptr, const unsigned short* __restrict__ csr_src,
    float4* __restrict__ stats, int Nn)
{
    const int wave = threadIdx.x >> 6, lane = threadIdx.x & 63;
    const int i = blockIdx.x * 4 + wave;
    if (i >= Nn) return;
    const int start = indptr[i], end = indptr[i + 1];
    const float ad0 = al_d[2 * i], ad1 = al_d[2 * i + 1];

    float m0 = -1e30f, m1 = -1e30f, den0 = 0.f, den1 = 0.f;
    for (int j = start + lane; j < end; j += 64) {
        int s = csr_src[j];
        float2 as = *(const float2*)(al_s + 2 * s);
        float e0 = as.x + ad0; e0 = e0 > 0.f ? e0 : NEG_SLOPE * e0;
        float e1 = as.y + ad1; e1 = e1 > 0.f ? e1 : NEG_SLOPE * e1;
        float n0 = fmaxf(m0, e0);
        den0 = den0 * __expf(m0 - n0) + __expf(e0 - n0);
        m0 = n0;
        float n1 = fmaxf(m1, e1);
        den1 = den1 * __expf(m1 - n1) + __expf(e1 - n1);
        m1 = n1;
    }
#pragma unroll
    for (int off = 32; off; off >>= 1) {
        float mo0 = __shfl_xor(m0, off), do0 = __shfl_xor(den0, off);
        float n0 = fmaxf(m0, mo0);
        den0 = den0 * __expf(m0 - n0) + do0 * __expf(mo0 - n0);
        m0 = n0;
        float mo1 = __shfl_xor(m1, off), do1 = __shfl_xor(den1, off);
        float n1 = fmaxf(m1, mo1);
        den1 = den1 * __expf(m1 - n1) + do1 * __expf(mo1 - n1);
        m1 = n1;
    }
    if (lane == 0) {
        float4 st;
        st.x = m0; st.y = m1;
        st.z = 1.f / den0; st.w = 1.f / den1;
        stats[i] = st;
    }
}

// ------- L1 slab gather: contiguous 2-MB column slabs pinned per XCD -------
// bufC is 32 slabs of [N][8] fp32 (2 MB each, CONTIGUOUS -> zero line waste,
// fits one XCD L2 with room for cached al_s). Grid: 4 phases x 8 s8 x 256
// node-blocks; slice = phase*8 + (blockIdx%8) so each XCD streams exactly one
// resident slab per phase. One lane per node per slice (8 cols); edges summed
// sequentially in j order -> bitwise-identical accumulation to round-1 path.
// csr/stats loads + output stores nontemporal (no intra-slice reuse; must not
// evict the slab). al_s (512 KB, heavy random reuse) stays cached.
__global__ __launch_bounds__(256) void gat_gather_slab(
    const float* __restrict__ hslab,
    const float* __restrict__ al_s, const float* __restrict__ al_d,
    const f32x4* __restrict__ stats,
    const int* __restrict__ indptr, const unsigned short* __restrict__ csr_src,
    const float* __restrict__ bias,
    unsigned short* __restrict__ outHi, unsigned short* __restrict__ outLo,
    int C, int HC)
{
    const int bid = blockIdx.x;
    const int s8 = bid & 7;
    const int rest = bid >> 3;
    const int nb = rest & 255;          // 256 node-blocks (256 nodes each)
    const int phase = rest >> 8;        // 0..3
    const int slice = phase * 8 + s8;   // 0..31

    const int lane = threadIdx.x & 63;
    const int wave = threadIdx.x >> 6;
    const int i = (nb * 4 + wave) * 64 + lane;   // node id
    const int ch = slice * 8;

    const int start = indptr[i], end = indptr[i + 1];
    const float ad0 = al_d[2 * i], ad1 = al_d[2 * i + 1];
    const f32x4 st = __builtin_nontemporal_load(stats + i);
    const float m0 = st[0], m1 = st[1], inv0 = st[2], inv1 = st[3];

    const bool k0h = (ch + 0) < C, k1h = (ch + 1) < C, k2h = (ch + 2) < C,
               k3h = (ch + 3) < C, k4h = (ch + 4) < C, k5h = (ch + 5) < C,
               k6h = (ch + 6) < C, k7h = (ch + 7) < C;

    float a0 = 0.f, a1 = 0.f, a2 = 0.f, a3 = 0.f;
    float a4 = 0.f, a5 = 0.f, a6 = 0.f, a7 = 0.f;
    const float* hb = hslab + (size_t)slice * ((size_t)N_NODES * 8);

    for (int j = start; j < end; ++j) {
        int s = __builtin_nontemporal_load(csr_src + j);
        float2 as = *(const float2*)(al_s + 2 * s);
        float e0 = as.x + ad0; e0 = e0 > 0.f ? e0 : NEG_SLOPE * e0;
        float e1 = as.y + ad1; e1 = e1 > 0.f ? e1 : NEG_SLOPE * e1;
        float w0 = __expf(e0 - m0) * inv0;
        float w1 = __expf(e1 - m1) * inv1;
        const float* hr = hb + (size_t)s * 8;
        float4 hA = *(const float4*)hr;
        float4 hB = *(const float4*)(hr + 4);
        a0 = fmaf(k0h ? w0 : w1, hA.x, a0);
        a1 = fmaf(k1h ? w0 : w1, hA.y, a1);
        a2 = fmaf(k2h ? w0 : w1, hA.z, a2);
        a3 = fmaf(k3h ? w0 : w1, hA.w, a3);
        a4 = fmaf(k4h ? w0 : w1, hB.x, a4);
        a5 = fmaf(k5h ? w0 : w1, hB.y, a5);
        a6 = fmaf(k6h ? w0 : w1, hB.z, a6);
        a7 = fmaf(k7h ? w0 : w1, hB.w, a7);
    }

    float acc[8] = {a0, a1, a2, a3, a4, a5, a6, a7};
    unsigned short hi8[8], lo8[8];
#pragma unroll
    for (int k = 0; k < 8; ++k) {
        float bv = (ch + k < HC) ? bias[ch + k] : 0.f;
        float v = fmaxf(acc[k] + bv, 0.f);
        unsigned short h = f2bf(v);
        hi8[k] = h;
        lo8[k] = f2bf(v - bf2f(h));
    }
    u32x4 H, L;
    H[0] = (unsigned)hi8[0] | ((unsigned)hi8[1] << 16);
    H[1] = (unsigned)hi8[2] | ((unsigned)hi8[3] << 16);
    H[2] = (unsigned)hi8[4] | ((unsigned)hi8[5] << 16);
    H[3] = (unsigned)hi8[6] | ((unsigned)hi8[7] << 16);
    L[0] = (unsigned)lo8[0] | ((unsigned)lo8[1] << 16);
    L[1] = (unsigned)lo8[2] | ((unsigned)lo8[3] << 16);
    L[2] = (unsigned)lo8[4] | ((unsigned)lo8[5] << 16);
    L[3] = (unsigned)lo8[6] | ((unsigned)lo8[7] << 16);
    __builtin_nontemporal_store(H, (u32x4*)(outHi + (size_t)i * 256 + ch));
    __builtin_nontemporal_store(L, (u32x4*)(outLo + (size_t)i * 256 + ch));
}

// ------- fused stats+gather (L2-4, one wave per node) -------
template<int LPE>
__global__ __launch_bounds__(256) void gat_gather_fused(
    const float* __restrict__ hlin,
    const float* __restrict__ al_s, const float* __restrict__ al_d,
    const int* __restrict__ indptr, const unsigned short* __restrict__ csr_src,
    const float* __restrict__ bias,
    unsigned short* __restrict__ outHi, unsigned short* __restrict__ outLo,
    int ldo, int Nn, int C, int HC, int HCpad)
{
    constexpr int G = 64 / LPE;
    const int wave = threadIdx.x >> 6, lane = threadIdx.x & 63;
    const int i = blockIdx.x * 4 + wave;
    if (i >= Nn) return;
    const int start = indptr[i], end = indptr[i + 1];
    const float ad0 = al_d[2 * i], ad1 = al_d[2 * i + 1];

    float m0 = -1e30f, m1 = -1e30f, den0 = 0.f, den1 = 0.f;
    for (int j = start + lane; j < end; j += 64) {
        int s = csr_src[j];
        float2 as = *(const float2*)(al_s + 2 * s);
        float e0 = as.x + ad0; e0 = e0 > 0.f ? e0 : NEG_SLOPE * e0;
        float e1 = as.y + ad1; e1 = e1 > 0.f ? e1 : NEG_SLOPE * e1;
        float n0 = fmaxf(m0, e0);
        den0 = den0 * __expf(m0 - n0) + __expf(e0 - n0);
        m0 = n0;
        float n1 = fmaxf(m1, e1);
        den1 = den1 * __expf(m1 - n1) + __expf(e1 - n1);
        m1 = n1;
    }
#pragma unroll
    for (int off = 32; off; off >>= 1) {
        float mo0 = __shfl_xor(m0, off), do0 = __shfl_xor(den0, off);
        float n0 = fmaxf(m0, mo0);
        den0 = den0 * __expf(m0 - n0) + do0 * __expf(mo0 - n0);
        m0 = n0;
        float mo1 = __shfl_xor(m1, off), do1 = __shfl_xor(den1, off);
        float n1 = fmaxf(m1, mo1);
        den1 = den1 * __expf(m1 - n1) + do1 * __expf(mo1 - n1);
        m1 = n1;
    }
    const float inv0 = 1.f / den0, inv1 = 1.f / den1;

    const int l = lane % LPE;
    const int g = lane / LPE;
    const int ch4 = l * 4;
    const bool chA = ch4 < HCpad;
    float a0 = 0.f, a1 = 0.f, a2 = 0.f, a3 = 0.f;
    const bool h0 = (ch4 + 0) < C, h1 = (ch4 + 1) < C,
               h2 = (ch4 + 2) < C, h3 = (ch4 + 3) < C;

    for (int jb = start; jb < end; jb += 4 * G) {
#pragma unroll
        for (int u = 0; u < 4; ++u) {
            int j = jb + u * G + g;
            int jj = j < end ? j : end - 1;   // end-1 >= start (self-loop)
            int s = csr_src[jj];
            float2 as = *(const float2*)(al_s + 2 * s);
            float e0 = as.x + ad0; e0 = e0 > 0.f ? e0 : NEG_SLOPE * e0;
            float e1 = as.y + ad1; e1 = e1 > 0.f ? e1 : NEG_SLOPE * e1;
            float w0 = __expf(e0 - m0) * inv0;
            float w1 = __expf(e1 - m1) * inv1;
            if (j >= end) { w0 = 0.f; w1 = 0.f; }
            const float* hr = hlin + (size_t)s * HCpad;
            float4 h = chA ? *(const float4*)(hr + ch4)
                           : make_float4(0.f, 0.f, 0.f, 0.f);
            a0 = fmaf(h0 ? w0 : w1, h.x, a0);
            a1 = fmaf(h1 ? w0 : w1, h.y, a1);
            a2 = fmaf(h2 ? w0 : w1, h.z, a2);
            a3 = fmaf(h3 ? w0 : w1, h.w, a3);
        }
    }
#pragma unroll
    for (int off = LPE; off < 64; off <<= 1) {
        a0 += __shfl_xor(a0, off);
        a1 += __shfl_xor(a1, off);
        a2 += __shfl_xor(a2, off);
        a3 += __shfl_xor(a3, off);
    }
    if (g == 0 && chA) {
        float bx = (ch4 + 0 < HC) ? bias[ch4 + 0] : 0.f;
        float by = (ch4 + 1 < HC) ? bias[ch4 + 1] : 0.f;
        float bz = (ch4 + 2 < HC) ? bias[ch4 + 2] : 0.f;
        float bw = (ch4 + 3 < HC) ? bias[ch4 + 3] : 0.f;
        float v0 = fmaxf(a0 + bx, 0.f);
        float v1 = fmaxf(a1 + by, 0.f);
        float v2 = fmaxf(a2 + bz, 0.f);
        float v3 = fmaxf(a3 + bw, 0.f);
        ushort4 h, lo;
        h.x = f2bf(v0); lo.x = f2bf(v0 - bf2f(h.x));
        h.y = f2bf(v1); lo.y = f2bf(v1 - bf2f(h.y));
        h.z = f2bf(v2); lo.z = f2bf(v2 - bf2f(h.z));
        h.w = f2bf(v3); lo.w = f2bf(v3 - bf2f(h.w));
        nt_store_us4(outHi + (size_t)i * ldo + ch4, h);
        nt_store_us4(outLo + (size_t)i * ldo + ch4, lo);
    }
    for (int z = HCpad + lane * 4; z < ldo; z += 256) {
        ushort4 zz; zz.x = zz.y = zz.z = zz.w = 0;
        *(ushort4*)(outHi + (size_t)i * ldo + z) = zz;
        *(ushort4*)(outLo + (size_t)i * ldo + z) = zz;
    }
}

// ---------------- CSR build (with self-loops folded in) ----------------
__global__ void hist_self_k(const int* __restrict__ dst, int E,
                            int* __restrict__ counts, int n)
{
    int gid = blockIdx.x * blockDim.x + threadIdx.x;
    if (gid < E) atomicAdd(&counts[dst[gid]], 1);
    else if (gid < E + n) atomicAdd(&counts[gid - E], 1);
}

__global__ void scan_block_k(const int* __restrict__ in, int* __restrict__ out,
                             int* __restrict__ bsum, int n)
{
    __shared__ int sh[256];
    int gid = blockIdx.x * 256 + threadIdx.x;
    int v = (gid < n) ? in[gid] : 0;
    sh[threadIdx.x] = v;
    __syncthreads();
    for (int off = 1; off < 256; off <<= 1) {
        int t = (threadIdx.x >= off) ? sh[threadIdx.x - off] : 0;
        __syncthreads();
        sh[threadIdx.x] += t;
        __syncthreads();
    }
    int incl = sh[threadIdx.x];
    if (gid < n) out[gid] = incl - v;
    if (threadIdx.x == 255) bsum[blockIdx.x] = incl;
}

__global__ void scan_tops_k(const int* __restrict__ bsum, int* __restrict__ boff)
{
    __shared__ int sh[256];
    int v = bsum[threadIdx.x];
    sh[threadIdx.x] = v;
    __syncthreads();
    for (int off = 1; off < 256; off <<= 1) {
        int t = (threadIdx.x >= off) ? sh[threadIdx.x - off] : 0;
        __syncthreads();
        sh[threadIdx.x] += t;
        __syncthreads();
    }
    boff[threadIdx.x] = sh[threadIdx.x] - v;
}

__global__ void scan_add_k(int* __restrict__ indptr, const int* __restrict__ boff,
                           int n, int Etot)
{
    int gid = blockIdx.x * 256 + threadIdx.x;
    if (gid < n) indptr[gid] += boff[blockIdx.x];
    if (gid == 0) indptr[n] = Etot;
}

__global__ void fill_all_k(const int* __restrict__ src, const int* __restrict__ dst,
                           int E, const int* __restrict__ indptr,
                           int* __restrict__ cursor,
                           unsigned short* __restrict__ csr_src, int n)
{
    int gid = blockIdx.x * blockDim.x + threadIdx.x;
    if (gid < E) {
        int d = dst[gid];
        int pos = atomicAdd(&cursor[d], 1);
        csr_src[indptr[d] + pos] = (unsigned short)src[gid];
    } else if (gid < E + n) {
        int i = gid - E;
        int pos = atomicAdd(&cursor[i], 1);
        csr_src[indptr[i] + pos] = (unsigned short)i;
    }
}

// ---------------- launch ----------------
extern "C" void kernel_launch(void* const* d_in, const int* in_sizes, int n_in,
                              void* d_out, int out_size, void* d_ws, size_t ws_size,
                              hipStream_t stream)
{
    (void)in_sizes; (void)n_in; (void)out_size; (void)ws_size;
    const int N = N_NODES;
    const int E = N_EDGES;
    const int Etot = E + N;

    const float* x = (const float*)d_in[0];
    const int* ei = (const int*)d_in[1];
    const float* Wc[4] = {(const float*)d_in[3], (const float*)d_in[7],
                          (const float*)d_in[11], (const float*)d_in[15]};
    const float* AS[4] = {(const float*)d_in[4], (const float*)d_in[8],
                          (const float*)d_in[12], (const float*)d_in[16]};
    const float* AD[4] = {(const float*)d_in[5], (const float*)d_in[9],
                          (const float*)d_in[13], (const float*)d_in[17]};
    const float* Bc[4] = {(const float*)d_in[6], (const float*)d_in[10],
                          (const float*)d_in[14], (const float*)d_in[18]};
    const float* LW[4] = {(const float*)d_in[19], (const float*)d_in[21],
                          (const float*)d_in[23], (const float*)d_in[25]};
    const float* LB[4] = {(const float*)d_in[20], (const float*)d_in[22],
                          (const float*)d_in[24], (const float*)d_in[26]};

    char* w = (char*)d_ws;
    auto alloc = [&](size_t bytes) -> char* {
        char* p = w; w += (bytes + 255) & ~(size_t)255; return p;
    };
    float* bufC = (float*)alloc((size_t)N * 256 * 4);   // GEMM out: L1 = 32 slabs [N][8]
    unsigned short* actHi = (unsigned short*)alloc((size_t)N * 256 * 2);
    unsigned short* actLo = (unsigned short*)alloc((size_t)N * 256 * 2);
    unsigned short* csr = (unsigned short*)alloc((size_t)Etot * 2);  // u16 src ids
    float4* stats = (float4*)alloc((size_t)N * 16);                  // m0,m1,inv0,inv1
    // alSD (4 layers x [alS|alD]) + counts/cursor: contiguous, single memset
    float* alSD = (float*)alloc((size_t)N * 4 * 4 * 4 + (size_t)N * 2 * 4);
    int* cnt2   = (int*)(alSD + (size_t)N * 16);
    int* counts = cnt2;
    int* cursor = cnt2 + N;
    int* indptr = (int*)alloc((size_t)(N + 8) * 4);
    int* bsum   = (int*)alloc(1024);
    int* boff   = (int*)alloc(1024);

    const int KpConv[4] = {352, 256, 160, 128};
    const int NpConv[4] = {256, 192, 128, 64};
    const int KpLin[4]  = {512, 224, 128, 128};
    const int NpLin[4]  = {256, 128, 128, 64};
    unsigned short *WtHi[4], *WtLo[4], *LtHi[4], *LtLo[4];
    for (int l = 0; l < 4; ++l) {
        WtHi[l] = (unsigned short*)alloc((size_t)NpConv[l] * KpConv[l] * 2);
        WtLo[l] = (unsigned short*)alloc((size_t)NpConv[l] * KpConv[l] * 2);
    }
    for (int l = 0; l < 4; ++l) {
        LtHi[l] = (unsigned short*)alloc((size_t)NpLin[l] * KpLin[l] * 2);
        LtLo[l] = (unsigned short*)alloc((size_t)NpLin[l] * KpLin[l] * 2);
    }

    const int* esrc = ei;
    const int* edst = ei + E;

    // ---- CSR by dst incl. self-loops; zero al buffers + counts in one memset ----
    hipMemsetAsync(alSD, 0, (size_t)N * 4 * 4 * 4 + (size_t)N * 2 * 4, stream);
    hist_self_k<<<(E + N) / 256, 256, 0, stream>>>(edst, E, counts, N);
    scan_block_k<<<N / 256, 256, 0, stream>>>(counts, indptr, bsum, N);
    scan_tops_k<<<1, 256, 0, stream>>>(bsum, boff);
    scan_add_k<<<N / 256, 256, 0, stream>>>(indptr, boff, N, Etot);
    fill_all_k<<<(E + N) / 256, 256, 0, stream>>>(esrc, edst, E, indptr, cursor, csr, N);

    // ---- weight decompose (one kernel for all 8) ----
    const int Kc[4] = {336, 250, 150, 100}, Nc[4] = {250, 150, 100, 60};
    const int Kl[4] = {480, 200, 100, 100}, Nl[4] = {200, 100, 100, 29};
    WtJobs jobs;
    int nb = 0;
    for (int l = 0; l < 4; ++l) {
        jobs.j[l] = {Wc[l], WtHi[l], WtLo[l], Kc[l], Nc[l], KpConv[l], 0, nb};
        nb += NpConv[l];
    }
    for (int l = 0; l < 4; ++l) {
        jobs.j[4 + l] = {LW[l], LtHi[l], LtLo[l], Kl[l], Nl[l], KpLin[l],
                         l == 0 ? 1 : 0, nb};
        nb += NpLin[l];
    }
    wt_decomp_all<<<nb, 256, 0, stream>>>(jobs);

    // ---- 4 GAT layers ----
    const int HCp[4]  = {256, 152, 100, 60};   // fp32 GEMM-out leading dim
    const int ldoA[4] = {256, 160, 128, 64};   // bf16 act leading dim (= next Kp)
    const int ldaA[4] = {336, 256, 160, 128};  // A leading dim into GEMM
    for (int l = 0; l < 4; ++l) {
        int C = Nc[l] / 2, HC = Nc[l];
        float* alS = alSD + (size_t)l * N * 4;
        float* alD = alS + (size_t)N * 2;
        if (l == 0) {
            gemm_mfma<128><<<dim3(2, N / 128), 256, 0, stream>>>(
                x, 336, nullptr, nullptr, 336, 352,
                WtHi[0], WtLo[0], nullptr, 0,
                bufC, nullptr, nullptr, HCp[0], HCp[0], 0, 1 /*slab8*/,
                AS[0], AD[0], alS, alD, C, HC);
        } else if (l == 1) {
            gemm_mfma<64><<<dim3(3, N / 128), 256, 0, stream>>>(
                nullptr, 0, actHi, actLo, ldaA[1], KpConv[1],
                WtHi[1], WtLo[1], nullptr, 0,
                bufC, nullptr, nullptr, HCp[1], HCp[1], 0, 0,
                AS[1], AD[1], alS, alD, C, HC);
        } else if (l == 2) {
            gemm_mfma<128><<<dim3(1, N / 128), 256, 0, stream>>>(
                nullptr, 0, actHi, actLo, ldaA[2], KpConv[2],
                WtHi[2], WtLo[2], nullptr, 0,
                bufC, nullptr, nullptr, HCp[2], HCp[2], 0, 0,
                AS[2], AD[2], alS, alD, C, HC);
        } else {
            gemm_mfma<64><<<dim3(1, N / 128), 256, 0, stream>>>(
                nullptr, 0, actHi, actLo, ldaA[3], KpConv[3],
                WtHi[3], WtLo[3], nullptr, 0,
                bufC, nullptr, nullptr, HCp[3], HCp[3], 0, 0,
                AS[3], AD[3], alS, alD, C, HC);
        }
        if (l == 0) {
            attn_stats<<<N / 4, 256, 0, stream>>>(alS, alD, indptr, csr, stats, N);
            gat_gather_slab<<<4 * 256 * 8, 256, 0, stream>>>(
                bufC, alS, alD, (const f32x4*)stats, indptr, csr, Bc[0],
                actHi, actLo, C, HC);
        } else if (l == 1) {
            gat_gather_fused<64><<<N / 4, 256, 0, stream>>>(
                bufC, alS, alD, indptr, csr, Bc[1],
                actHi, actLo, ldoA[1], N, C, HC, HCp[1]);
        } else if (l == 2) {
            gat_gather_fused<32><<<N / 4, 256, 0, stream>>>(
                bufC, alS, alD, indptr, csr, Bc[2],
                actHi, actLo, ldoA[2], N, C, HC, HCp[2]);
        } else {
            gat_gather_fused<16><<<N / 4, 256, 0, stream>>>(
                bufC, alS, alD, indptr, csr, Bc[3],
                actHi, actLo, ldoA[3], N, C, HC, HCp[3]);
        }
    }

    // ---- MLP head, fused: [8192,480(512 remapped)] -> 200 -> 100 -> 100 -> 29 ----
    mlp_fused<<<8192 / 32, 256, 0, stream>>>(
        actHi, actLo,
        LtHi[0], LtLo[0], LtHi[1], LtLo[1],
        LtHi[2], LtLo[2], LtHi[3], LtLo[3],
        LB[0], LB[1], LB[2], LB[3],
        (float*)d_out);
}

// Round 4
// 1053.812 us; speedup vs baseline: 1.4464x; 1.4464x over previous
//
#include <hip/hip_runtime.h>
#include <hip/hip_bf16.h>
#include <stdint.h>

#define N_NODES 65536
#define N_EDGES (N_NODES * 16)
#define NEG_SLOPE 0.2f

typedef short bf16x8 __attribute__((ext_vector_type(8)));   // 8 bf16 in 4 VGPRs
typedef float f32x4 __attribute__((ext_vector_type(4)));
typedef unsigned int u32x2 __attribute__((ext_vector_type(2)));

__device__ __forceinline__ unsigned short f2bf(float f) {
    unsigned u = __float_as_uint(f);
    u += 0x7fffu + ((u >> 16) & 1u);       // RNE
    return (unsigned short)(u >> 16);
}
__device__ __forceinline__ float bf2f(unsigned short h) {
    return __uint_as_float(((unsigned)h) << 16);
}
__device__ __forceinline__ void load_lds16(const void* g, void* l) {
    __builtin_amdgcn_global_load_lds(
        (const __attribute__((address_space(1))) unsigned int*)g,
        (__attribute__((address_space(3))) unsigned int*)l, 16, 0, 0);
}
// nontemporal 8B store of a ushort4 (streaming output; keep L2 for gather rows)
__device__ __forceinline__ void nt_store_us4(unsigned short* p, ushort4 v) {
    u32x2 d;
    d.x = (unsigned)v.x | ((unsigned)v.y << 16);
    d.y = (unsigned)v.z | ((unsigned)v.w << 16);
    __builtin_nontemporal_store(d, (u32x2*)p);
}

// ---------------- MFMA GEMM: C[M,Nw] = A[M,Kp] @ Wt^T (+bias,+relu) ----------------
// A: fp32 (A32 path, converted during staging) or bf16 hi/lo pair.
// Wt transposed [n][Kp] bf16 hi/lo, zero-padded.
// Split-bf16: acc += Ahi*Bhi + Alo*Bhi + Ahi*Blo  (fp32 MFMA accumulate).
// Block 256 = 4 waves; tile 128(M) x TN(N), TN in {64,128}; BK=32.
// If asrc != null: also computes per-row attention dots al_s/al_d (atomicAdd).
template<int TN>
__global__ __launch_bounds__(256) void gemm_mfma(
    const float* __restrict__ A32, int KA,
    const unsigned short* __restrict__ Ahi, const unsigned short* __restrict__ Alo,
    int lda, int Kp,
    const unsigned short* __restrict__ Bhi, const unsigned short* __restrict__ Blo,
    const float* __restrict__ bias, int Nbias,
    float* __restrict__ C32,
    unsigned short* __restrict__ Chi, unsigned short* __restrict__ Clo,
    int ldc, int Nw, int relu,
    const float* __restrict__ asrc, const float* __restrict__ adst,
    float* __restrict__ alS, float* __restrict__ alD, int Cal, int HCal)
{
    constexpr int NI = TN / 32;                 // N-frags per wave
    __shared__ unsigned short sAhi[128 * 32], sAlo[128 * 32];
    __shared__ unsigned short sBhi[TN * 32],  sBlo[TN * 32];
    __shared__ float sAl[128][2][4];
    const int tid = threadIdx.x;
    const int wave = tid >> 6, lane = tid & 63;
    const int row0 = blockIdx.y * 128;
    const int col0 = blockIdx.x * TN;
    const int wm = (wave & 1) * 64, wn = (wave >> 1) * (TN / 2);
    const int mlane = lane & 15, q = lane >> 4;

    f32x4 acc[4][NI];
#pragma unroll
    for (int a = 0; a < 4; ++a)
#pragma unroll
        for (int b = 0; b < NI; ++b) acc[a][b] = (f32x4){0.f, 0.f, 0.f, 0.f};

    for (int k0 = 0; k0 < Kp; k0 += 32) {
        __syncthreads();
        if (A32) {
            // fp32 -> bf16 hi/lo conversion staging (layer 1 only)
            const int r = tid >> 1, cbase = (tid & 1) * 16;
            const float* Ap = A32 + (size_t)(row0 + r) * lda;
#pragma unroll
            for (int j = 0; j < 4; ++j) {
                int kc = k0 + cbase + j * 4;
                float4 v = make_float4(0.f, 0.f, 0.f, 0.f);
                if (kc < KA) v = *(const float4*)(Ap + kc);
                ushort4 h, l;
                h.x = f2bf(v.x); l.x = f2bf(v.x - bf2f(h.x));
                h.y = f2bf(v.y); l.y = f2bf(v.y - bf2f(h.y));
                h.z = f2bf(v.z); l.z = f2bf(v.z - bf2f(h.z));
                h.w = f2bf(v.w); l.w = f2bf(v.w - bf2f(h.w));
                *(ushort4*)(sAhi + r * 32 + cbase + j * 4) = h;
                *(ushort4*)(sAlo + r * 32 + cbase + j * 4) = l;
            }
        } else {
            // async global->LDS, 16B/lane; LDS dst = wave-uniform base + lane*16
#pragma unroll
            for (int cc = 0; cc < 2; ++cc) {
                int c = wave * 2 + cc;                 // 8 chunks of 16 rows
                int r = c * 16 + (lane >> 2);
                size_t goff = (size_t)(row0 + r) * lda + k0 + (lane & 3) * 8;
                load_lds16(Ahi + goff, sAhi + c * 512);
                load_lds16(Alo + goff, sAlo + c * 512);
            }
        }
        {
#pragma unroll
            for (int cc = 0; cc < TN / 64; ++cc) {
                int c = wave * (TN / 64) + cc;         // TN/16 chunks of 16 rows
                int r = c * 16 + (lane >> 2);
                size_t goff = (size_t)(col0 + r) * Kp + k0 + (lane & 3) * 8;
                load_lds16(Bhi + goff, sBhi + c * 512);
                load_lds16(Blo + goff, sBlo + c * 512);
            }
        }
        __syncthreads();

        bf16x8 ah[4], al[4], bh[NI], bl[NI];
#pragma unroll
        for (int mi = 0; mi < 4; ++mi) {
            int m = wm + mi * 16 + mlane;
            ah[mi] = *(const bf16x8*)(sAhi + m * 32 + q * 8);
            al[mi] = *(const bf16x8*)(sAlo + m * 32 + q * 8);
        }
#pragma unroll
        for (int ni = 0; ni < NI; ++ni) {
            int n = wn + ni * 16 + mlane;
            bh[ni] = *(const bf16x8*)(sBhi + n * 32 + q * 8);
            bl[ni] = *(const bf16x8*)(sBlo + n * 32 + q * 8);
        }
#pragma unroll
        for (int mi = 0; mi < 4; ++mi)
#pragma unroll
            for (int ni = 0; ni < NI; ++ni) {
                acc[mi][ni] = __builtin_amdgcn_mfma_f32_16x16x32_bf16(ah[mi], bh[ni], acc[mi][ni], 0, 0, 0);
                acc[mi][ni] = __builtin_amdgcn_mfma_f32_16x16x32_bf16(al[mi], bh[ni], acc[mi][ni], 0, 0, 0);
                acc[mi][ni] = __builtin_amdgcn_mfma_f32_16x16x32_bf16(ah[mi], bl[ni], acc[mi][ni], 0, 0, 0);
            }
    }

    // epilogue: C/D frag layout col=lane&15, row=(lane>>4)*4+reg
#pragma unroll
    for (int ni = 0; ni < NI; ++ni) {
        int col = col0 + wn + ni * 16 + mlane;
        if (col >= Nw) continue;
        float bv = (bias && col < Nbias) ? bias[col] : 0.f;
#pragma unroll
        for (int mi = 0; mi < 4; ++mi) {
#pragma unroll
            for (int reg = 0; reg < 4; ++reg) {
                int row = row0 + wm + mi * 16 + q * 4 + reg;
                float v = acc[mi][ni][reg] + bv;
                if (relu) v = fmaxf(v, 0.f);
                size_t off = (size_t)row * ldc + col;
                if (Chi) {
                    unsigned short h = f2bf(v);
                    Chi[off] = h;
                    Clo[off] = f2bf(v - bf2f(h));
                } else {
                    C32[off] = v;
                }
            }
        }
    }

    // fused attention-logit dots: al_s[row,h] += sum_c h[row,c]*a_s[h,c], same for a_d
    if (asrc) {
        float asv[NI], adv[NI];
        bool head0[NI];
#pragma unroll
        for (int ni = 0; ni < NI; ++ni) {
            int col = col0 + wn + ni * 16 + mlane;
            bool valid = col < HCal;
            head0[ni] = col < Cal;
            asv[ni] = valid ? asrc[col] : 0.f;
            adv[ni] = valid ? adst[col] : 0.f;
        }
#pragma unroll
        for (int mi = 0; mi < 4; ++mi) {
#pragma unroll
            for (int reg = 0; reg < 4; ++reg) {
                float s0 = 0.f, s1 = 0.f, d0 = 0.f, d1 = 0.f;
#pragma unroll
                for (int ni = 0; ni < NI; ++ni) {
                    float v = acc[mi][ni][reg];
                    if (head0[ni]) { s0 += v * asv[ni]; d0 += v * adv[ni]; }
                    else           { s1 += v * asv[ni]; d1 += v * adv[ni]; }
                }
#pragma unroll
                for (int off = 1; off < 16; off <<= 1) {
                    s0 += __shfl_xor(s0, off); s1 += __shfl_xor(s1, off);
                    d0 += __shfl_xor(d0, off); d1 += __shfl_xor(d1, off);
                }
                if (mlane == 0) {
                    int rl = wm + mi * 16 + q * 4 + reg;
                    int slot = wave >> 1;
                    sAl[rl][slot][0] = s0; sAl[rl][slot][1] = s1;
                    sAl[rl][slot][2] = d0; sAl[rl][slot][3] = d1;
                }
            }
        }
        __syncthreads();
        if (tid < 128) {
            int row = row0 + tid;
            float v0 = sAl[tid][0][0] + sAl[tid][1][0];
            float v1 = sAl[tid][0][1] + sAl[tid][1][1];
            float v2 = sAl[tid][0][2] + sAl[tid][1][2];
            float v3 = sAl[tid][0][3] + sAl[tid][1][3];
            atomicAdd(&alS[row * 2 + 0], v0);
            atomicAdd(&alS[row * 2 + 1], v1);
            atomicAdd(&alD[row * 2 + 0], v2);
            atomicAdd(&alD[row * 2 + 1], v3);
        }
    }
}

// ------------- fused MLP head: 4 layers in one kernel, 32 rows/block -------------
template<int NI>
__device__ __forceinline__ void mlp_layer(
    const unsigned short* aHi, const unsigned short* aLo, int ldaS, int K,
    const unsigned short* __restrict__ Bhi, const unsigned short* __restrict__ Blo,
    int Kp,
    unsigned short* sBh, unsigned short* sBl,
    const float* __restrict__ bias, int Nbias, int colBase,
    unsigned short* oHi, unsigned short* oLo, int ldo, int Nstore,
    float* __restrict__ gOut, int row0, int relu,
    int wave, int lane)
{
    const int mlane = lane & 15, q = lane >> 4;
    const int wm = (wave & 1) * 16;
    const int wn = (wave >> 1) * (NI * 16);
    f32x4 acc[NI];
#pragma unroll
    for (int b = 0; b < NI; ++b) acc[b] = (f32x4){0.f, 0.f, 0.f, 0.f};

    for (int k0 = 0; k0 < K; k0 += 32) {
        __syncthreads();
        for (int c = wave; c < NI * 2; c += 4) {   // stage B rows (N = NI*32)
            int r = c * 16 + (lane >> 2);
            size_t goff = (size_t)r * Kp + k0 + (lane & 3) * 8;
            load_lds16(Bhi + goff, sBh + c * 512);
            load_lds16(Blo + goff, sBl + c * 512);
        }
        __syncthreads();

        bf16x8 ah, al, bh[NI], bl[NI];
        ah = *(const bf16x8*)(aHi + (wm + mlane) * ldaS + k0 + q * 8);
        al = *(const bf16x8*)(aLo + (wm + mlane) * ldaS + k0 + q * 8);
#pragma unroll
        for (int ni = 0; ni < NI; ++ni) {
            int n = wn + ni * 16 + mlane;
            bh[ni] = *(const bf16x8*)(sBh + n * 32 + q * 8);
            bl[ni] = *(const bf16x8*)(sBl + n * 32 + q * 8);
        }
#pragma unroll
        for (int ni = 0; ni < NI; ++ni) {
            acc[ni] = __builtin_amdgcn_mfma_f32_16x16x32_bf16(ah, bh[ni], acc[ni], 0, 0, 0);
            acc[ni] = __builtin_amdgcn_mfma_f32_16x16x32_bf16(al, bh[ni], acc[ni], 0, 0, 0);
            acc[ni] = __builtin_amdgcn_mfma_f32_16x16x32_bf16(ah, bl[ni], acc[ni], 0, 0, 0);
        }
    }
    __syncthreads();   // all reads of aHi/aLo done before caller overwrites

#pragma unroll
    for (int ni = 0; ni < NI; ++ni) {
        int colg = colBase + wn + ni * 16 + mlane;
        float bv = (colg < Nbias) ? bias[colg] : 0.f;
#pragma unroll
        for (int reg = 0; reg < 4; ++reg) {
            int row = wm + q * 4 + reg;
            float v = acc[ni][reg] + bv;
            if (relu) v = fmaxf(v, 0.f);
            if (gOut) {
                if (colg < 29) gOut[(size_t)(row0 + row) * 29 + colg] = v;
            } else if (colg < Nstore) {
                unsigned short h = f2bf(v);
                oHi[row * ldo + colg] = h;
                oLo[row * ldo + colg] = f2bf(v - bf2f(h));
            }
        }
    }
}

__global__ __launch_bounds__(256) void mlp_fused(
    const unsigned short* __restrict__ actHi, const unsigned short* __restrict__ actLo,
    const unsigned short* __restrict__ L1h, const unsigned short* __restrict__ L1l,
    const unsigned short* __restrict__ L2h, const unsigned short* __restrict__ L2l,
    const unsigned short* __restrict__ L3h, const unsigned short* __restrict__ L3l,
    const unsigned short* __restrict__ L4h, const unsigned short* __restrict__ L4l,
    const float* __restrict__ B1, const float* __restrict__ B2,
    const float* __restrict__ B3, const float* __restrict__ B4,
    float* __restrict__ out)
{
    __shared__ unsigned short b1h[32 * 224], b1l[32 * 224];   // L1 out / L3 out
    __shared__ unsigned short b2h[32 * 128], b2l[32 * 128];   // L2 out
    __shared__ unsigned short sAh[32 * 32],  sAl[32 * 32];    // L1 A staging
    __shared__ unsigned short sBh[128 * 32], sBl[128 * 32];   // B staging
    const int tid = threadIdx.x;
    const int wave = tid >> 6, lane = tid & 63;
    const int row0 = blockIdx.x * 32;
    const int mlane = lane & 15, q = lane >> 4;
    const int wm = (wave & 1) * 16;
    const int wn = (wave >> 1) * 64;

    // ---- layer 1: [32,512] @ L1^T -> b1 [32,224], two 128-col tiles ----
    for (int nt = 0; nt < 2; ++nt) {
        const unsigned short* Bh = L1h + (size_t)nt * 128 * 512;
        const unsigned short* Bl = L1l + (size_t)nt * 128 * 512;
        f32x4 acc[4];
#pragma unroll
        for (int b = 0; b < 4; ++b) acc[b] = (f32x4){0.f, 0.f, 0.f, 0.f};
        for (int k0 = 0; k0 < 512; k0 += 32) {
            __syncthreads();
            for (int c = wave; c < 2; c += 4) {      // A: 32 rows
                int r = c * 16 + (lane >> 2);
                size_t goff = (size_t)(row0 + r) * 512 + k0 + (lane & 3) * 8;
                load_lds16(actHi + goff, sAh + c * 512);
                load_lds16(actLo + goff, sAl + c * 512);
            }
            for (int c = wave; c < 8; c += 4) {      // B: 128 rows
                int r = c * 16 + (lane >> 2);
                size_t goff = (size_t)r * 512 + k0 + (lane & 3) * 8;
                load_lds16(Bh + goff, sBh + c * 512);
                load_lds16(Bl + goff, sBl + c * 512);
            }
            __syncthreads();
            bf16x8 ah = *(const bf16x8*)(sAh + (wm + mlane) * 32 + q * 8);
            bf16x8 al = *(const bf16x8*)(sAl + (wm + mlane) * 32 + q * 8);
#pragma unroll
            for (int ni = 0; ni < 4; ++ni) {
                int n = wn + ni * 16 + mlane;
                bf16x8 bh = *(const bf16x8*)(sBh + n * 32 + q * 8);
                bf16x8 bl = *(const bf16x8*)(sBl + n * 32 + q * 8);
                acc[ni] = __builtin_amdgcn_mfma_f32_16x16x32_bf16(ah, bh, acc[ni], 0, 0, 0);
                acc[ni] = __builtin_amdgcn_mfma_f32_16x16x32_bf16(al, bh, acc[ni], 0, 0, 0);
                acc[ni] = __builtin_amdgcn_mfma_f32_16x16x32_bf16(ah, bl, acc[ni], 0, 0, 0);
            }
        }
        __syncthreads();
#pragma unroll
        for (int ni = 0; ni < 4; ++ni) {
            int colg = nt * 128 + wn + ni * 16 + mlane;
            float bv = (colg < 200) ? B1[colg] : 0.f;
#pragma unroll
            for (int reg = 0; reg < 4; ++reg) {
                int row = wm + q * 4 + reg;
                float v = fmaxf(acc[ni][reg] + bv, 0.f);
                if (colg < 224) {
                    unsigned short h = f2bf(v);
                    b1h[row * 224 + colg] = h;
                    b1l[row * 224 + colg] = f2bf(v - bf2f(h));
                }
            }
        }
    }
    __syncthreads();

    // ---- layer 2: b1[32,224] -> b2[32,128] ----
    mlp_layer<4>(b1h, b1l, 224, 224, L2h, L2l, 224, sBh, sBl,
                 B2, 100, 0, b2h, b2l, 128, 128, nullptr, 0, 1, wave, lane);
    __syncthreads();
    // ---- layer 3: b2[32,128] -> b1[32,128] (reuse, ld 128) ----
    mlp_layer<4>(b2h, b2l, 128, 128, L3h, L3l, 128, sBh, sBl,
                 B3, 100, 0, b1h, b1l, 128, 128, nullptr, 0, 1, wave, lane);
    __syncthreads();
    // ---- layer 4: b1[32,128] -> out[32,29] fp32 ----
    mlp_layer<2>(b1h, b1l, 128, 128, L4h, L4l, 128, sBh, sBl,
                 B4, 29, 0, nullptr, nullptr, 0, 0, out, row0, 0, wave, lane);
}

// ---------------- weight transpose + bf16 hi/lo decompose (all 8 in one) ----------
struct WtJob {
    const float* W; unsigned short* Whi; unsigned short* Wlo;
    int K, N, Kp, remap, nb0;
};
struct WtJobs { WtJob j[8]; };

__global__ void wt_decomp_all(WtJobs jobs)
{
    int b = blockIdx.x;
    int idx = 0;
#pragma unroll
    for (int i = 1; i < 8; ++i)
        if (b >= jobs.j[i].nb0) idx = i;
    WtJob jb = jobs.j[idx];
    int n = b - jb.nb0;
    for (int k = threadIdx.x; k < jb.Kp; k += 256) {
        int ks = k, valid = 1;
        if (jb.remap) {
            int bb = k >> 6, r = k & 63;
            if (r < 60) ks = bb * 60 + r; else valid = 0;
        }
        float v = 0.f;
        if (valid && ks < jb.K && n < jb.N) v = jb.W[(size_t)ks * jb.N + n];
        unsigned short h = f2bf(v);
        jb.Whi[(size_t)n * jb.Kp + k] = h;
        jb.Wlo[(size_t)n * jb.Kp + k] = f2bf(v - bf2f(h));
    }
}

// ------- fused stats+gather (all 4 layers, one wave per node) -------
// Stats pass: online segment-softmax (m, den), butterfly-combined -> bitwise
// stable weights. Gather pass: recompute w = exp(e-m)*inv per edge, accumulate
// w * h[src]. UNR edges in flight per group (MLP depth); per-lane j-sequence
// (ascending, j == g mod G) is unroll-invariant -> bitwise-identical output.
template<int LPE, int UNR>
__global__ __launch_bounds__(256) void gat_gather_fused(
    const float* __restrict__ hlin,
    const float* __restrict__ al_s, const float* __restrict__ al_d,
    const int* __restrict__ indptr, const unsigned short* __restrict__ csr_src,
    const float* __restrict__ bias,
    unsigned short* __restrict__ outHi, unsigned short* __restrict__ outLo,
    int ldo, int Nn, int C, int HC, int HCpad)
{
    constexpr int G = 64 / LPE;
    const int wave = threadIdx.x >> 6, lane = threadIdx.x & 63;
    const int i = blockIdx.x * 4 + wave;
    if (i >= Nn) return;
    const int start = indptr[i], end = indptr[i + 1];
    const float ad0 = al_d[2 * i], ad1 = al_d[2 * i + 1];

    float m0 = -1e30f, m1 = -1e30f, den0 = 0.f, den1 = 0.f;
    for (int j = start + lane; j < end; j += 64) {
        int s = csr_src[j];
        float2 as = *(const float2*)(al_s + 2 * s);
        float e0 = as.x + ad0; e0 = e0 > 0.f ? e0 : NEG_SLOPE * e0;
        float e1 = as.y + ad1; e1 = e1 > 0.f ? e1 : NEG_SLOPE * e1;
        float n0 = fmaxf(m0, e0);
        den0 = den0 * __expf(m0 - n0) + __expf(e0 - n0);
        m0 = n0;
        float n1 = fmaxf(m1, e1);
        den1 = den1 * __expf(m1 - n1) + __expf(e1 - n1);
        m1 = n1;
    }
#pragma unroll
    for (int off = 32; off; off >>= 1) {
        float mo0 = __shfl_xor(m0, off), do0 = __shfl_xor(den0, off);
        float n0 = fmaxf(m0, mo0);
        den0 = den0 * __expf(m0 - n0) + do0 * __expf(mo0 - n0);
        m0 = n0;
        float mo1 = __shfl_xor(m1, off), do1 = __shfl_xor(den1, off);
        float n1 = fmaxf(m1, mo1);
        den1 = den1 * __expf(m1 - n1) + do1 * __expf(mo1 - n1);
        m1 = n1;
    }
    const float inv0 = 1.f / den0, inv1 = 1.f / den1;

    const int l = lane % LPE;
    const int g = lane / LPE;
    const int ch4 = l * 4;
    const bool chA = ch4 < HCpad;
    float a0 = 0.f, a1 = 0.f, a2 = 0.f, a3 = 0.f;
    const bool h0 = (ch4 + 0) < C, h1 = (ch4 + 1) < C,
               h2 = (ch4 + 2) < C, h3 = (ch4 + 3) < C;

    for (int jb = start; jb < end; jb += UNR * G) {
#pragma unroll
        for (int u = 0; u < UNR; ++u) {
            int j = jb + u * G + g;
            if (G == 1 && j >= end) break;    // wave-uniform early-out
            int jj = j < end ? j : end - 1;   // end-1 >= start (self-loop)
            int s = csr_src[jj];
            float2 as = *(const float2*)(al_s + 2 * s);
            float e0 = as.x + ad0; e0 = e0 > 0.f ? e0 : NEG_SLOPE * e0;
            float e1 = as.y + ad1; e1 = e1 > 0.f ? e1 : NEG_SLOPE * e1;
            float w0 = __expf(e0 - m0) * inv0;
            float w1 = __expf(e1 - m1) * inv1;
            if (G != 1 && j >= end) { w0 = 0.f; w1 = 0.f; }
            const float* hr = hlin + (size_t)s * HCpad;
            float4 h = chA ? *(const float4*)(hr + ch4)
                           : make_float4(0.f, 0.f, 0.f, 0.f);
            a0 = fmaf(h0 ? w0 : w1, h.x, a0);
            a1 = fmaf(h1 ? w0 : w1, h.y, a1);
            a2 = fmaf(h2 ? w0 : w1, h.z, a2);
            a3 = fmaf(h3 ? w0 : w1, h.w, a3);
        }
    }
#pragma unroll
    for (int off = LPE; off < 64; off <<= 1) {
        a0 += __shfl_xor(a0, off);
        a1 += __shfl_xor(a1, off);
        a2 += __shfl_xor(a2, off);
        a3 += __shfl_xor(a3, off);
    }
    if (g == 0 && chA) {
        float bx = (ch4 + 0 < HC) ? bias[ch4 + 0] : 0.f;
        float by = (ch4 + 1 < HC) ? bias[ch4 + 1] : 0.f;
        float bz = (ch4 + 2 < HC) ? bias[ch4 + 2] : 0.f;
        float bw = (ch4 + 3 < HC) ? bias[ch4 + 3] : 0.f;
        float v0 = fmaxf(a0 + bx, 0.f);
        float v1 = fmaxf(a1 + by, 0.f);
        float v2 = fmaxf(a2 + bz, 0.f);
        float v3 = fmaxf(a3 + bw, 0.f);
        ushort4 h, lo;
        h.x = f2bf(v0); lo.x = f2bf(v0 - bf2f(h.x));
        h.y = f2bf(v1); lo.y = f2bf(v1 - bf2f(h.y));
        h.z = f2bf(v2); lo.z = f2bf(v2 - bf2f(h.z));
        h.w = f2bf(v3); lo.w = f2bf(v3 - bf2f(h.w));
        nt_store_us4(outHi + (size_t)i * ldo + ch4, h);
        nt_store_us4(outLo + (size_t)i * ldo + ch4, lo);
    }
    for (int z = HCpad + lane * 4; z < ldo; z += 256) {
        ushort4 zz; zz.x = zz.y = zz.z = zz.w = 0;
        *(ushort4*)(outHi + (size_t)i * ldo + z) = zz;
        *(ushort4*)(outLo + (size_t)i * ldo + z) = zz;
    }
}

// ---------------- CSR build (with self-loops folded in) ----------------
__global__ void hist_self_k(const int* __restrict__ dst, int E,
                            int* __restrict__ counts, int n)
{
    int gid = blockIdx.x * blockDim.x + threadIdx.x;
    if (gid < E) atomicAdd(&counts[dst[gid]], 1);
    else if (gid < E + n) atomicAdd(&counts[gid - E], 1);
}

__global__ void scan_block_k(const int* __restrict__ in, int* __restrict__ out,
                             int* __restrict__ bsum, int n)
{
    __shared__ int sh[256];
    int gid = blockIdx.x * 256 + threadIdx.x;
    int v = (gid < n) ? in[gid] : 0;
    sh[threadIdx.x] = v;
    __syncthreads();
    for (int off = 1; off < 256; off <<= 1) {
        int t = (threadIdx.x >= off) ? sh[threadIdx.x - off] : 0;
        __syncthreads();
        sh[threadIdx.x] += t;
        __syncthreads();
    }
    int incl = sh[threadIdx.x];
    if (gid < n) out[gid] = incl - v;
    if (threadIdx.x == 255) bsum[blockIdx.x] = incl;
}

__global__ void scan_tops_k(const int* __restrict__ bsum, int* __restrict__ boff)
{
    __shared__ int sh[256];
    int v = bsum[threadIdx.x];
    sh[threadIdx.x] = v;
    __syncthreads();
    for (int off = 1; off < 256; off <<= 1) {
        int t = (threadIdx.x >= off) ? sh[threadIdx.x - off] : 0;
        __syncthreads();
        sh[threadIdx.x] += t;
        __syncthreads();
    }
    boff[threadIdx.x] = sh[threadIdx.x] - v;
}

__global__ void scan_add_k(int* __restrict__ indptr, const int* __restrict__ boff,
                           int n, int Etot)
{
    int gid = blockIdx.x * 256 + threadIdx.x;
    if (gid < n) indptr[gid] += boff[blockIdx.x];
    if (gid == 0) indptr[n] = Etot;
}

__global__ void fill_all_k(const int* __restrict__ src, const int* __restrict__ dst,
                           int E, const int* __restrict__ indptr,
                           int* __restrict__ cursor,
                           unsigned short* __restrict__ csr_src, int n)
{
    int gid = blockIdx.x * blockDim.x + threadIdx.x;
    if (gid < E) {
        int d = dst[gid];
        int pos = atomicAdd(&cursor[d], 1);
        csr_src[indptr[d] + pos] = (unsigned short)src[gid];
    } else if (gid < E + n) {
        int i = gid - E;
        int pos = atomicAdd(&cursor[i], 1);
        csr_src[indptr[i] + pos] = (unsigned short)i;
    }
}

// ---------------- launch ----------------
extern "C" void kernel_launch(void* const* d_in, const int* in_sizes, int n_in,
                              void* d_out, int out_size, void* d_ws, size_t ws_size,
                              hipStream_t stream)
{
    (void)in_sizes; (void)n_in; (void)out_size; (void)ws_size;
    const int N = N_NODES;
    const int E = N_EDGES;
    const int Etot = E + N;

    const float* x = (const float*)d_in[0];
    const int* ei = (const int*)d_in[1];
    const float* Wc[4] = {(const float*)d_in[3], (const float*)d_in[7],
                          (const float*)d_in[11], (const float*)d_in[15]};
    const float* AS[4] = {(const float*)d_in[4], (const float*)d_in[8],
                          (const float*)d_in[12], (const float*)d_in[16]};
    const float* AD[4] = {(const float*)d_in[5], (const float*)d_in[9],
                          (const float*)d_in[13], (const float*)d_in[17]};
    const float* Bc[4] = {(const float*)d_in[6], (const float*)d_in[10],
                          (const float*)d_in[14], (const float*)d_in[18]};
    const float* LW[4] = {(const float*)d_in[19], (const float*)d_in[21],
                          (const float*)d_in[23], (const float*)d_in[25]};
    const float* LB[4] = {(const float*)d_in[20], (const float*)d_in[22],
                          (const float*)d_in[24], (const float*)d_in[26]};

    char* w = (char*)d_ws;
    auto alloc = [&](size_t bytes) -> char* {
        char* p = w; w += (bytes + 255) & ~(size_t)255; return p;
    };
    float* bufC = (float*)alloc((size_t)N * 256 * 4);            // GEMM out, fp32 (ld 256 for L1)
    unsigned short* actHi = (unsigned short*)alloc((size_t)N * 256 * 2);
    unsigned short* actLo = (unsigned short*)alloc((size_t)N * 256 * 2);
    unsigned short* csr = (unsigned short*)alloc((size_t)Etot * 2);  // u16 src ids
    // alSD (4 layers x [alS|alD]) + counts/cursor: contiguous, single memset
    float* alSD = (float*)alloc((size_t)N * 4 * 4 * 4 + (size_t)N * 2 * 4);
    int* cnt2   = (int*)(alSD + (size_t)N * 16);
    int* counts = cnt2;
    int* cursor = cnt2 + N;
    int* indptr = (int*)alloc((size_t)(N + 8) * 4);
    int* bsum   = (int*)alloc(1024);
    int* boff   = (int*)alloc(1024);

    const int KpConv[4] = {352, 256, 160, 128};
    const int NpConv[4] = {256, 192, 128, 64};
    const int KpLin[4]  = {512, 224, 128, 128};
    const int NpLin[4]  = {256, 128, 128, 64};
    unsigned short *WtHi[4], *WtLo[4], *LtHi[4], *LtLo[4];
    for (int l = 0; l < 4; ++l) {
        WtHi[l] = (unsigned short*)alloc((size_t)NpConv[l] * KpConv[l] * 2);
        WtLo[l] = (unsigned short*)alloc((size_t)NpConv[l] * KpConv[l] * 2);
    }
    for (int l = 0; l < 4; ++l) {
        LtHi[l] = (unsigned short*)alloc((size_t)NpLin[l] * KpLin[l] * 2);
        LtLo[l] = (unsigned short*)alloc((size_t)NpLin[l] * KpLin[l] * 2);
    }

    const int* esrc = ei;
    const int* edst = ei + E;

    // ---- CSR by dst incl. self-loops; zero al buffers + counts in one memset ----
    hipMemsetAsync(alSD, 0, (size_t)N * 4 * 4 * 4 + (size_t)N * 2 * 4, stream);
    hist_self_k<<<(E + N) / 256, 256, 0, stream>>>(edst, E, counts, N);
    scan_block_k<<<N / 256, 256, 0, stream>>>(counts, indptr, bsum, N);
    scan_tops_k<<<1, 256, 0, stream>>>(bsum, boff);
    scan_add_k<<<N / 256, 256, 0, stream>>>(indptr, boff, N, Etot);
    fill_all_k<<<(E + N) / 256, 256, 0, stream>>>(esrc, edst, E, indptr, cursor, csr, N);

    // ---- weight decompose (one kernel for all 8) ----
    const int Kc[4] = {336, 250, 150, 100}, Nc[4] = {250, 150, 100, 60};
    const int Kl[4] = {480, 200, 100, 100}, Nl[4] = {200, 100, 100, 29};
    WtJobs jobs;
    int nb = 0;
    for (int l = 0; l < 4; ++l) {
        jobs.j[l] = {Wc[l], WtHi[l], WtLo[l], Kc[l], Nc[l], KpConv[l], 0, nb};
        nb += NpConv[l];
    }
    for (int l = 0; l < 4; ++l) {
        jobs.j[4 + l] = {LW[l], LtHi[l], LtLo[l], Kl[l], Nl[l], KpLin[l],
                         l == 0 ? 1 : 0, nb};
        nb += NpLin[l];
    }
    wt_decomp_all<<<nb, 256, 0, stream>>>(jobs);

    // ---- 4 GAT layers (stats fused into every gather; no meta buffer) ----
    const int HCp[4]  = {256, 152, 100, 60};   // fp32 GEMM-out leading dim
    const int ldoA[4] = {256, 160, 128, 64};   // bf16 act leading dim (= next Kp)
    const int ldaA[4] = {336, 256, 160, 128};  // A leading dim into GEMM
    for (int l = 0; l < 4; ++l) {
        int C = Nc[l] / 2, HC = Nc[l];
        float* alS = alSD + (size_t)l * N * 4;
        float* alD = alS + (size_t)N * 2;
        if (l == 0) {
            gemm_mfma<128><<<dim3(2, N / 128), 256, 0, stream>>>(
                x, 336, nullptr, nullptr, 336, 352,
                WtHi[0], WtLo[0], nullptr, 0,
                bufC, nullptr, nullptr, HCp[0], HCp[0], 0,
                AS[0], AD[0], alS, alD, C, HC);
        } else if (l == 1) {
            gemm_mfma<64><<<dim3(3, N / 128), 256, 0, stream>>>(
                nullptr, 0, actHi, actLo, ldaA[1], KpConv[1],
                WtHi[1], WtLo[1], nullptr, 0,
                bufC, nullptr, nullptr, HCp[1], HCp[1], 0,
                AS[1], AD[1], alS, alD, C, HC);
        } else if (l == 2) {
            gemm_mfma<128><<<dim3(1, N / 128), 256, 0, stream>>>(
                nullptr, 0, actHi, actLo, ldaA[2], KpConv[2],
                WtHi[2], WtLo[2], nullptr, 0,
                bufC, nullptr, nullptr, HCp[2], HCp[2], 0,
                AS[2], AD[2], alS, alD, C, HC);
        } else {
            gemm_mfma<64><<<dim3(1, N / 128), 256, 0, stream>>>(
                nullptr, 0, actHi, actLo, ldaA[3], KpConv[3],
                WtHi[3], WtLo[3], nullptr, 0,
                bufC, nullptr, nullptr, HCp[3], HCp[3], 0,
                AS[3], AD[3], alS, alD, C, HC);
        }
        if (l == 0) {
            gat_gather_fused<64, 8><<<N / 4, 256, 0, stream>>>(
                bufC, alS, alD, indptr, csr, Bc[0],
                actHi, actLo, ldoA[0], N, C, HC, HCp[0]);
        } else if (l == 1) {
            gat_gather_fused<64, 8><<<N / 4, 256, 0, stream>>>(
                bufC, alS, alD, indptr, csr, Bc[1],
                actHi, actLo, ldoA[1], N, C, HC, HCp[1]);
        } else if (l == 2) {
            gat_gather_fused<32, 8><<<N / 4, 256, 0, stream>>>(
                bufC, alS, alD, indptr, csr, Bc[2],
                actHi, actLo, ldoA[2], N, C, HC, HCp[2]);
        } else {
            gat_gather_fused<16, 8><<<N / 4, 256, 0, stream>>>(
                bufC, alS, alD, indptr, csr, Bc[3],
                actHi, actLo, ldoA[3], N, C, HC, HCp[3]);
        }
    }

    // ---- MLP head, fused: [8192,480(512 remapped)] -> 200 -> 100 -> 100 -> 29 ----
    mlp_fused<<<8192 / 32, 256, 0, stream>>>(
        actHi, actLo,
        LtHi[0], LtLo[0], LtHi[1], LtLo[1],
        LtHi[2], LtLo[2], LtHi[3], LtLo[3],
        LB[0], LB[1], LB[2], LB[3],
        (float*)d_out);
}

// Round 5
// 838.795 us; speedup vs baseline: 1.8171x; 1.2563x over previous
//
#include <hip/hip_runtime.h>
#include <hip/hip_bf16.h>
#include <stdint.h>

#define N_NODES 65536
#define N_EDGES (N_NODES * 16)
#define NEG_SLOPE 0.2f

typedef short bf16x8 __attribute__((ext_vector_type(8)));   // 8 bf16 in 4 VGPRs
typedef float f32x4 __attribute__((ext_vector_type(4)));
typedef unsigned int u32x2 __attribute__((ext_vector_type(2)));
typedef _Float16 f16x4 __attribute__((ext_vector_type(4))); // 4 fp16 = 8B

__device__ __forceinline__ unsigned short f2bf(float f) {
    unsigned u = __float_as_uint(f);
    u += 0x7fffu + ((u >> 16) & 1u);       // RNE
    return (unsigned short)(u >> 16);
}
__device__ __forceinline__ float bf2f(unsigned short h) {
    return __uint_as_float(((unsigned)h) << 16);
}
__device__ __forceinline__ unsigned short f2h(float f) {
    _Float16 h = (_Float16)f;              // v_cvt_f16_f32, RNE
    union { _Float16 h; unsigned short u; } cv; cv.h = h; return cv.u;
}
__device__ __forceinline__ void load_lds16(const void* g, void* l) {
    __builtin_amdgcn_global_load_lds(
        (const __attribute__((address_space(1))) unsigned int*)g,
        (__attribute__((address_space(3))) unsigned int*)l, 16, 0, 0);
}
// nontemporal 8B store of a ushort4 (streaming output; keep L2 for gather rows)
__device__ __forceinline__ void nt_store_us4(unsigned short* p, ushort4 v) {
    u32x2 d;
    d.x = (unsigned)v.x | ((unsigned)v.y << 16);
    d.y = (unsigned)v.z | ((unsigned)v.w << 16);
    __builtin_nontemporal_store(d, (u32x2*)p);
}

// ---------------- MFMA GEMM: C[M,Nw] = A[M,Kp] @ Wt^T ----------------
// A: fp32 (A32 path, converted during staging) or bf16 hi/lo pair.
// Wt transposed [n][Kp] bf16 hi/lo, zero-padded.
// Split-bf16: acc += Ahi*Bhi + Alo*Bhi + Ahi*Blo  (fp32 MFMA accumulate).
// C output: fp16 (RNE) — gather input; halves gather fill traffic vs fp32.
// If asrc != null: also computes per-row attention dots al_s/al_d in FP32
// (atomicAdd) — softmax weights therefore unchanged vs the fp32-C version.
template<int TN>
__global__ __launch_bounds__(256) void gemm_mfma(
    const float* __restrict__ A32, int KA,
    const unsigned short* __restrict__ Ahi, const unsigned short* __restrict__ Alo,
    int lda, int Kp,
    const unsigned short* __restrict__ Bhi, const unsigned short* __restrict__ Blo,
    unsigned short* __restrict__ C16,
    int ldc, int Nw,
    const float* __restrict__ asrc, const float* __restrict__ adst,
    float* __restrict__ alS, float* __restrict__ alD, int Cal, int HCal)
{
    constexpr int NI = TN / 32;                 // N-frags per wave
    __shared__ unsigned short sAhi[128 * 32], sAlo[128 * 32];
    __shared__ unsigned short sBhi[TN * 32],  sBlo[TN * 32];
    __shared__ float sAl[128][2][4];
    const int tid = threadIdx.x;
    const int wave = tid >> 6, lane = tid & 63;
    const int row0 = blockIdx.y * 128;
    const int col0 = blockIdx.x * TN;
    const int wm = (wave & 1) * 64, wn = (wave >> 1) * (TN / 2);
    const int mlane = lane & 15, q = lane >> 4;

    f32x4 acc[4][NI];
#pragma unroll
    for (int a = 0; a < 4; ++a)
#pragma unroll
        for (int b = 0; b < NI; ++b) acc[a][b] = (f32x4){0.f, 0.f, 0.f, 0.f};

    for (int k0 = 0; k0 < Kp; k0 += 32) {
        __syncthreads();
        if (A32) {
            // fp32 -> bf16 hi/lo conversion staging (layer 1 only)
            const int r = tid >> 1, cbase = (tid & 1) * 16;
            const float* Ap = A32 + (size_t)(row0 + r) * lda;
#pragma unroll
            for (int j = 0; j < 4; ++j) {
                int kc = k0 + cbase + j * 4;
                float4 v = make_float4(0.f, 0.f, 0.f, 0.f);
                if (kc < KA) v = *(const float4*)(Ap + kc);
                ushort4 h, l;
                h.x = f2bf(v.x); l.x = f2bf(v.x - bf2f(h.x));
                h.y = f2bf(v.y); l.y = f2bf(v.y - bf2f(h.y));
                h.z = f2bf(v.z); l.z = f2bf(v.z - bf2f(h.z));
                h.w = f2bf(v.w); l.w = f2bf(v.w - bf2f(h.w));
                *(ushort4*)(sAhi + r * 32 + cbase + j * 4) = h;
                *(ushort4*)(sAlo + r * 32 + cbase + j * 4) = l;
            }
        } else {
            // async global->LDS, 16B/lane; LDS dst = wave-uniform base + lane*16
#pragma unroll
            for (int cc = 0; cc < 2; ++cc) {
                int c = wave * 2 + cc;                 // 8 chunks of 16 rows
                int r = c * 16 + (lane >> 2);
                size_t goff = (size_t)(row0 + r) * lda + k0 + (lane & 3) * 8;
                load_lds16(Ahi + goff, sAhi + c * 512);
                load_lds16(Alo + goff, sAlo + c * 512);
            }
        }
        {
#pragma unroll
            for (int cc = 0; cc < TN / 64; ++cc) {
                int c = wave * (TN / 64) + cc;         // TN/16 chunks of 16 rows
                int r = c * 16 + (lane >> 2);
                size_t goff = (size_t)(col0 + r) * Kp + k0 + (lane & 3) * 8;
                load_lds16(Bhi + goff, sBhi + c * 512);
                load_lds16(Blo + goff, sBlo + c * 512);
            }
        }
        __syncthreads();

        bf16x8 ah[4], al[4], bh[NI], bl[NI];
#pragma unroll
        for (int mi = 0; mi < 4; ++mi) {
            int m = wm + mi * 16 + mlane;
            ah[mi] = *(const bf16x8*)(sAhi + m * 32 + q * 8);
            al[mi] = *(const bf16x8*)(sAlo + m * 32 + q * 8);
        }
#pragma unroll
        for (int ni = 0; ni < NI; ++ni) {
            int n = wn + ni * 16 + mlane;
            bh[ni] = *(const bf16x8*)(sBhi + n * 32 + q * 8);
            bl[ni] = *(const bf16x8*)(sBlo + n * 32 + q * 8);
        }
#pragma unroll
        for (int mi = 0; mi < 4; ++mi)
#pragma unroll
            for (int ni = 0; ni < NI; ++ni) {
                acc[mi][ni] = __builtin_amdgcn_mfma_f32_16x16x32_bf16(ah[mi], bh[ni], acc[mi][ni], 0, 0, 0);
                acc[mi][ni] = __builtin_amdgcn_mfma_f32_16x16x32_bf16(al[mi], bh[ni], acc[mi][ni], 0, 0, 0);
                acc[mi][ni] = __builtin_amdgcn_mfma_f32_16x16x32_bf16(ah[mi], bl[ni], acc[mi][ni], 0, 0, 0);
            }
    }

    // epilogue: C/D frag layout col=lane&15, row=(lane>>4)*4+reg; fp16 store
#pragma unroll
    for (int ni = 0; ni < NI; ++ni) {
        int col = col0 + wn + ni * 16 + mlane;
        if (col >= Nw) continue;
#pragma unroll
        for (int mi = 0; mi < 4; ++mi) {
#pragma unroll
            for (int reg = 0; reg < 4; ++reg) {
                int row = row0 + wm + mi * 16 + q * 4 + reg;
                C16[(size_t)row * ldc + col] = f2h(acc[mi][ni][reg]);
            }
        }
    }

    // fused attention-logit dots: al_s[row,h] += sum_c h[row,c]*a_s[h,c], same for a_d
    if (asrc) {
        float asv[NI], adv[NI];
        bool head0[NI];
#pragma unroll
        for (int ni = 0; ni < NI; ++ni) {
            int col = col0 + wn + ni * 16 + mlane;
            bool valid = col < HCal;
            head0[ni] = col < Cal;
            asv[ni] = valid ? asrc[col] : 0.f;
            adv[ni] = valid ? adst[col] : 0.f;
        }
#pragma unroll
        for (int mi = 0; mi < 4; ++mi) {
#pragma unroll
            for (int reg = 0; reg < 4; ++reg) {
                float s0 = 0.f, s1 = 0.f, d0 = 0.f, d1 = 0.f;
#pragma unroll
                for (int ni = 0; ni < NI; ++ni) {
                    float v = acc[mi][ni][reg];
                    if (head0[ni]) { s0 += v * asv[ni]; d0 += v * adv[ni]; }
                    else           { s1 += v * asv[ni]; d1 += v * adv[ni]; }
                }
#pragma unroll
                for (int off = 1; off < 16; off <<= 1) {
                    s0 += __shfl_xor(s0, off); s1 += __shfl_xor(s1, off);
                    d0 += __shfl_xor(d0, off); d1 += __shfl_xor(d1, off);
                }
                if (mlane == 0) {
                    int rl = wm + mi * 16 + q * 4 + reg;
                    int slot = wave >> 1;
                    sAl[rl][slot][0] = s0; sAl[rl][slot][1] = s1;
                    sAl[rl][slot][2] = d0; sAl[rl][slot][3] = d1;
                }
            }
        }
        __syncthreads();
        if (tid < 128) {
            int row = row0 + tid;
            float v0 = sAl[tid][0][0] + sAl[tid][1][0];
            float v1 = sAl[tid][0][1] + sAl[tid][1][1];
            float v2 = sAl[tid][0][2] + sAl[tid][1][2];
            float v3 = sAl[tid][0][3] + sAl[tid][1][3];
            atomicAdd(&alS[row * 2 + 0], v0);
            atomicAdd(&alS[row * 2 + 1], v1);
            atomicAdd(&alD[row * 2 + 0], v2);
            atomicAdd(&alD[row * 2 + 1], v3);
        }
    }
}

// ------------- fused MLP head: 4 layers in one kernel, 32 rows/block -------------
template<int NI>
__device__ __forceinline__ void mlp_layer(
    const unsigned short* aHi, const unsigned short* aLo, int ldaS, int K,
    const unsigned short* __restrict__ Bhi, const unsigned short* __restrict__ Blo,
    int Kp,
    unsigned short* sBh, unsigned short* sBl,
    const float* __restrict__ bias, int Nbias, int colBase,
    unsigned short* oHi, unsigned short* oLo, int ldo, int Nstore,
    float* __restrict__ gOut, int row0, int relu,
    int wave, int lane)
{
    const int mlane = lane & 15, q = lane >> 4;
    const int wm = (wave & 1) * 16;
    const int wn = (wave >> 1) * (NI * 16);
    f32x4 acc[NI];
#pragma unroll
    for (int b = 0; b < NI; ++b) acc[b] = (f32x4){0.f, 0.f, 0.f, 0.f};

    for (int k0 = 0; k0 < K; k0 += 32) {
        __syncthreads();
        for (int c = wave; c < NI * 2; c += 4) {   // stage B rows (N = NI*32)
            int r = c * 16 + (lane >> 2);
            size_t goff = (size_t)r * Kp + k0 + (lane & 3) * 8;
            load_lds16(Bhi + goff, sBh + c * 512);
            load_lds16(Blo + goff, sBl + c * 512);
        }
        __syncthreads();

        bf16x8 ah, al, bh[NI], bl[NI];
        ah = *(const bf16x8*)(aHi + (wm + mlane) * ldaS + k0 + q * 8);
        al = *(const bf16x8*)(aLo + (wm + mlane) * ldaS + k0 + q * 8);
#pragma unroll
        for (int ni = 0; ni < NI; ++ni) {
            int n = wn + ni * 16 + mlane;
            bh[ni] = *(const bf16x8*)(sBh + n * 32 + q * 8);
            bl[ni] = *(const bf16x8*)(sBl + n * 32 + q * 8);
        }
#pragma unroll
        for (int ni = 0; ni < NI; ++ni) {
            acc[ni] = __builtin_amdgcn_mfma_f32_16x16x32_bf16(ah, bh[ni], acc[ni], 0, 0, 0);
            acc[ni] = __builtin_amdgcn_mfma_f32_16x16x32_bf16(al, bh[ni], acc[ni], 0, 0, 0);
            acc[ni] = __builtin_amdgcn_mfma_f32_16x16x32_bf16(ah, bl[ni], acc[ni], 0, 0, 0);
        }
    }
    __syncthreads();   // all reads of aHi/aLo done before caller overwrites

#pragma unroll
    for (int ni = 0; ni < NI; ++ni) {
        int colg = colBase + wn + ni * 16 + mlane;
        float bv = (colg < Nbias) ? bias[colg] : 0.f;
#pragma unroll
        for (int reg = 0; reg < 4; ++reg) {
            int row = wm + q * 4 + reg;
            float v = acc[ni][reg] + bv;
            if (relu) v = fmaxf(v, 0.f);
            if (gOut) {
                if (colg < 29) gOut[(size_t)(row0 + row) * 29 + colg] = v;
            } else if (colg < Nstore) {
                unsigned short h = f2bf(v);
                oHi[row * ldo + colg] = h;
                oLo[row * ldo + colg] = f2bf(v - bf2f(h));
            }
        }
    }
}

__global__ __launch_bounds__(256) void mlp_fused(
    const unsigned short* __restrict__ actHi, const unsigned short* __restrict__ actLo,
    const unsigned short* __restrict__ L1h, const unsigned short* __restrict__ L1l,
    const unsigned short* __restrict__ L2h, const unsigned short* __restrict__ L2l,
    const unsigned short* __restrict__ L3h, const unsigned short* __restrict__ L3l,
    const unsigned short* __restrict__ L4h, const unsigned short* __restrict__ L4l,
    const float* __restrict__ B1, const float* __restrict__ B2,
    const float* __restrict__ B3, const float* __restrict__ B4,
    float* __restrict__ out)
{
    __shared__ unsigned short b1h[32 * 224], b1l[32 * 224];   // L1 out / L3 out
    __shared__ unsigned short b2h[32 * 128], b2l[32 * 128];   // L2 out
    __shared__ unsigned short sAh[32 * 32],  sAl[32 * 32];    // L1 A staging
    __shared__ unsigned short sBh[128 * 32], sBl[128 * 32];   // B staging
    const int tid = threadIdx.x;
    const int wave = tid >> 6, lane = tid & 63;
    const int row0 = blockIdx.x * 32;
    const int mlane = lane & 15, q = lane >> 4;
    const int wm = (wave & 1) * 16;
    const int wn = (wave >> 1) * 64;

    // ---- layer 1: [32,512] @ L1^T -> b1 [32,224], two 128-col tiles ----
    for (int nt = 0; nt < 2; ++nt) {
        const unsigned short* Bh = L1h + (size_t)nt * 128 * 512;
        const unsigned short* Bl = L1l + (size_t)nt * 128 * 512;
        f32x4 acc[4];
#pragma unroll
        for (int b = 0; b < 4; ++b) acc[b] = (f32x4){0.f, 0.f, 0.f, 0.f};
        for (int k0 = 0; k0 < 512; k0 += 32) {
            __syncthreads();
            for (int c = wave; c < 2; c += 4) {      // A: 32 rows
                int r = c * 16 + (lane >> 2);
                size_t goff = (size_t)(row0 + r) * 512 + k0 + (lane & 3) * 8;
                load_lds16(actHi + goff, sAh + c * 512);
                load_lds16(actLo + goff, sAl + c * 512);
            }
            for (int c = wave; c < 8; c += 4) {      // B: 128 rows
                int r = c * 16 + (lane >> 2);
                size_t goff = (size_t)r * 512 + k0 + (lane & 3) * 8;
                load_lds16(Bh + goff, sBh + c * 512);
                load_lds16(Bl + goff, sBl + c * 512);
            }
            __syncthreads();
            bf16x8 ah = *(const bf16x8*)(sAh + (wm + mlane) * 32 + q * 8);
            bf16x8 al = *(const bf16x8*)(sAl + (wm + mlane) * 32 + q * 8);
#pragma unroll
            for (int ni = 0; ni < 4; ++ni) {
                int n = wn + ni * 16 + mlane;
                bf16x8 bh = *(const bf16x8*)(sBh + n * 32 + q * 8);
                bf16x8 bl = *(const bf16x8*)(sBl + n * 32 + q * 8);
                acc[ni] = __builtin_amdgcn_mfma_f32_16x16x32_bf16(ah, bh, acc[ni], 0, 0, 0);
                acc[ni] = __builtin_amdgcn_mfma_f32_16x16x32_bf16(al, bh, acc[ni], 0, 0, 0);
                acc[ni] = __builtin_amdgcn_mfma_f32_16x16x32_bf16(ah, bl, acc[ni], 0, 0, 0);
            }
        }
        __syncthreads();
#pragma unroll
        for (int ni = 0; ni < 4; ++ni) {
            int colg = nt * 128 + wn + ni * 16 + mlane;
            float bv = (colg < 200) ? B1[colg] : 0.f;
#pragma unroll
            for (int reg = 0; reg < 4; ++reg) {
                int row = wm + q * 4 + reg;
                float v = fmaxf(acc[ni][reg] + bv, 0.f);
                if (colg < 224) {
                    unsigned short h = f2bf(v);
                    b1h[row * 224 + colg] = h;
                    b1l[row * 224 + colg] = f2bf(v - bf2f(h));
                }
            }
        }
    }
    __syncthreads();

    // ---- layer 2: b1[32,224] -> b2[32,128] ----
    mlp_layer<4>(b1h, b1l, 224, 224, L2h, L2l, 224, sBh, sBl,
                 B2, 100, 0, b2h, b2l, 128, 128, nullptr, 0, 1, wave, lane);
    __syncthreads();
    // ---- layer 3: b2[32,128] -> b1[32,128] (reuse, ld 128) ----
    mlp_layer<4>(b2h, b2l, 128, 128, L3h, L3l, 128, sBh, sBl,
                 B3, 100, 0, b1h, b1l, 128, 128, nullptr, 0, 1, wave, lane);
    __syncthreads();
    // ---- layer 4: b1[32,128] -> out[32,29] fp32 ----
    mlp_layer<2>(b1h, b1l, 128, 128, L4h, L4l, 128, sBh, sBl,
                 B4, 29, 0, nullptr, nullptr, 0, 0, out, row0, 0, wave, lane);
}

// ---------------- weight transpose + bf16 hi/lo decompose (all 8 in one) ----------
struct WtJob {
    const float* W; unsigned short* Whi; unsigned short* Wlo;
    int K, N, Kp, remap, nb0;
};
struct WtJobs { WtJob j[8]; };

__global__ void wt_decomp_all(WtJobs jobs)
{
    int b = blockIdx.x;
    int idx = 0;
#pragma unroll
    for (int i = 1; i < 8; ++i)
        if (b >= jobs.j[i].nb0) idx = i;
    WtJob jb = jobs.j[idx];
    int n = b - jb.nb0;
    for (int k = threadIdx.x; k < jb.Kp; k += 256) {
        int ks = k, valid = 1;
        if (jb.remap) {
            int bb = k >> 6, r = k & 63;
            if (r < 60) ks = bb * 60 + r; else valid = 0;
        }
        float v = 0.f;
        if (valid && ks < jb.K && n < jb.N) v = jb.W[(size_t)ks * jb.N + n];
        unsigned short h = f2bf(v);
        jb.Whi[(size_t)n * jb.Kp + k] = h;
        jb.Wlo[(size_t)n * jb.Kp + k] = f2bf(v - bf2f(h));
    }
}

// ------- fused stats+gather (all 4 layers, one wave per node) -------
// Stats pass: online segment-softmax (m, den), butterfly-combined -> weights
// computed from FP32 attention dots, unchanged vs the fp32-bufC version.
// Gather pass: per 64-edge chunk, weights are computed ONCE (wave-parallel,
// lane <-> edge jb+lane), then the column loop pulls {w0,w1,src} via __shfl.
// Chunk size 64 == 0 mod G, so edge->group assignment and per-group j-order
// are IDENTICAL to the previous per-lane-recompute version; padded slots
// contribute exact +0. Only change vs round-1: h is fp16 (halved fill bytes).
template<int LPE>
__global__ __launch_bounds__(256) void gat_gather_fused(
    const unsigned short* __restrict__ h16,
    const float* __restrict__ al_s, const float* __restrict__ al_d,
    const int* __restrict__ indptr, const unsigned short* __restrict__ csr_src,
    const float* __restrict__ bias,
    unsigned short* __restrict__ outHi, unsigned short* __restrict__ outLo,
    int ldo, int Nn, int C, int HC, int HCpad)
{
    constexpr int G = 64 / LPE;
    const int wave = threadIdx.x >> 6, lane = threadIdx.x & 63;
    const int i = blockIdx.x * 4 + wave;
    if (i >= Nn) return;
    const int start = indptr[i], end = indptr[i + 1];
    const float ad0 = al_d[2 * i], ad1 = al_d[2 * i + 1];

    float m0 = -1e30f, m1 = -1e30f, den0 = 0.f, den1 = 0.f;
    for (int j = start + lane; j < end; j += 64) {
        int s = csr_src[j];
        float2 as = *(const float2*)(al_s + 2 * s);
        float e0 = as.x + ad0; e0 = e0 > 0.f ? e0 : NEG_SLOPE * e0;
        float e1 = as.y + ad1; e1 = e1 > 0.f ? e1 : NEG_SLOPE * e1;
        float n0 = fmaxf(m0, e0);
        den0 = den0 * __expf(m0 - n0) + __expf(e0 - n0);
        m0 = n0;
        float n1 = fmaxf(m1, e1);
        den1 = den1 * __expf(m1 - n1) + __expf(e1 - n1);
        m1 = n1;
    }
#pragma unroll
    for (int off = 32; off; off >>= 1) {
        float mo0 = __shfl_xor(m0, off), do0 = __shfl_xor(den0, off);
        float n0 = fmaxf(m0, mo0);
        den0 = den0 * __expf(m0 - n0) + do0 * __expf(mo0 - n0);
        m0 = n0;
        float mo1 = __shfl_xor(m1, off), do1 = __shfl_xor(den1, off);
        float n1 = fmaxf(m1, mo1);
        den1 = den1 * __expf(m1 - n1) + do1 * __expf(mo1 - n1);
        m1 = n1;
    }
    const float inv0 = 1.f / den0, inv1 = 1.f / den1;

    const int l = lane % LPE;
    const int g = lane / LPE;
    const int ch4 = l * 4;
    const bool chA = ch4 < HCpad;
    float a0 = 0.f, a1 = 0.f, a2 = 0.f, a3 = 0.f;
    const bool c0 = (ch4 + 0) < C, c1 = (ch4 + 1) < C,
               c2 = (ch4 + 2) < C, c3 = (ch4 + 3) < C;

    for (int jb = start; jb < end; jb += 64) {
        // wave-parallel weight pre-pass: lane <-> edge jb+lane
        int jW = jb + lane;
        float pw0 = 0.f, pw1 = 0.f;
        int ps = 0;
        if (jW < end) {
            ps = csr_src[jW];
            float2 as = *(const float2*)(al_s + 2 * ps);
            float e0 = as.x + ad0; e0 = e0 > 0.f ? e0 : NEG_SLOPE * e0;
            float e1 = as.y + ad1; e1 = e1 > 0.f ? e1 : NEG_SLOPE * e1;
            pw0 = __expf(e0 - m0) * inv0;
            pw1 = __expf(e1 - m1) * inv1;
        }
        int nedge = end - jb; if (nedge > 64) nedge = 64;
        int nit = (nedge + G - 1) / G;
        for (int u = 0; u < nit; ++u) {
            int idx = u * G + g;               // lane holding this edge
            float w0 = __shfl(pw0, idx);       // idx>=nedge -> 0 (defaults)
            float w1 = __shfl(pw1, idx);
            int s = __shfl(ps, idx);
            float hx = 0.f, hy = 0.f, hz = 0.f, hw = 0.f;
            if (chA) {
                f16x4 hv = *(const f16x4*)(h16 + (size_t)s * HCpad + ch4);
                hx = (float)hv[0]; hy = (float)hv[1];
                hz = (float)hv[2]; hw = (float)hv[3];
            }
            a0 = fmaf(c0 ? w0 : w1, hx, a0);
            a1 = fmaf(c1 ? w0 : w1, hy, a1);
            a2 = fmaf(c2 ? w0 : w1, hz, a2);
            a3 = fmaf(c3 ? w0 : w1, hw, a3);
        }
    }
#pragma unroll
    for (int off = LPE; off < 64; off <<= 1) {
        a0 += __shfl_xor(a0, off);
        a1 += __shfl_xor(a1, off);
        a2 += __shfl_xor(a2, off);
        a3 += __shfl_xor(a3, off);
    }
    if (g == 0 && chA) {
        float bx = (ch4 + 0 < HC) ? bias[ch4 + 0] : 0.f;
        float by = (ch4 + 1 < HC) ? bias[ch4 + 1] : 0.f;
        float bz = (ch4 + 2 < HC) ? bias[ch4 + 2] : 0.f;
        float bw = (ch4 + 3 < HC) ? bias[ch4 + 3] : 0.f;
        float v0 = fmaxf(a0 + bx, 0.f);
        float v1 = fmaxf(a1 + by, 0.f);
        float v2 = fmaxf(a2 + bz, 0.f);
        float v3 = fmaxf(a3 + bw, 0.f);
        ushort4 h, lo;
        h.x = f2bf(v0); lo.x = f2bf(v0 - bf2f(h.x));
        h.y = f2bf(v1); lo.y = f2bf(v1 - bf2f(h.y));
        h.z = f2bf(v2); lo.z = f2bf(v2 - bf2f(h.z));
        h.w = f2bf(v3); lo.w = f2bf(v3 - bf2f(h.w));
        nt_store_us4(outHi + (size_t)i * ldo + ch4, h);
        nt_store_us4(outLo + (size_t)i * ldo + ch4, lo);
    }
    for (int z = HCpad + lane * 4; z < ldo; z += 256) {
        ushort4 zz; zz.x = zz.y = zz.z = zz.w = 0;
        *(ushort4*)(outHi + (size_t)i * ldo + z) = zz;
        *(ushort4*)(outLo + (size_t)i * ldo + z) = zz;
    }
}

// ---------------- CSR build (with self-loops folded in) ----------------
__global__ void hist_self_k(const int* __restrict__ dst, int E,
                            int* __restrict__ counts, int n)
{
    int gid = blockIdx.x * blockDim.x + threadIdx.x;
    if (gid < E) atomicAdd(&counts[dst[gid]], 1);
    else if (gid < E + n) atomicAdd(&counts[gid - E], 1);
}

__global__ void scan_block_k(const int* __restrict__ in, int* __restrict__ out,
                             int* __restrict__ bsum, int n)
{
    __shared__ int sh[256];
    int gid = blockIdx.x * 256 + threadIdx.x;
    int v = (gid < n) ? in[gid] : 0;
    sh[threadIdx.x] = v;
    __syncthreads();
    for (int off = 1; off < 256; off <<= 1) {
        int t = (threadIdx.x >= off) ? sh[threadIdx.x - off] : 0;
        __syncthreads();
        sh[threadIdx.x] += t;
        __syncthreads();
    }
    int incl = sh[threadIdx.x];
    if (gid < n) out[gid] = incl - v;
    if (threadIdx.x == 255) bsum[blockIdx.x] = incl;
}

__global__ void scan_tops_k(const int* __restrict__ bsum, int* __restrict__ boff)
{
    __shared__ int sh[256];
    int v = bsum[threadIdx.x];
    sh[threadIdx.x] = v;
    __syncthreads();
    for (int off = 1; off < 256; off <<= 1) {
        int t = (threadIdx.x >= off) ? sh[threadIdx.x - off] : 0;
        __syncthreads();
        sh[threadIdx.x] += t;
        __syncthreads();
    }
    boff[threadIdx.x] = sh[threadIdx.x] - v;
}

__global__ void scan_add_k(int* __restrict__ indptr, const int* __restrict__ boff,
                           int n, int Etot)
{
    int gid = blockIdx.x * 256 + threadIdx.x;
    if (gid < n) indptr[gid] += boff[blockIdx.x];
    if (gid == 0) indptr[n] = Etot;
}

__global__ void fill_all_k(const int* __restrict__ src, const int* __restrict__ dst,
                           int E, const int* __restrict__ indptr,
                           int* __restrict__ cursor,
                           unsigned short* __restrict__ csr_src, int n)
{
    int gid = blockIdx.x * blockDim.x + threadIdx.x;
    if (gid < E) {
        int d = dst[gid];
        int pos = atomicAdd(&cursor[d], 1);
        csr_src[indptr[d] + pos] = (unsigned short)src[gid];
    } else if (gid < E + n) {
        int i = gid - E;
        int pos = atomicAdd(&cursor[i], 1);
        csr_src[indptr[i] + pos] = (unsigned short)i;
    }
}

// ---------------- launch ----------------
extern "C" void kernel_launch(void* const* d_in, const int* in_sizes, int n_in,
                              void* d_out, int out_size, void* d_ws, size_t ws_size,
                              hipStream_t stream)
{
    (void)in_sizes; (void)n_in; (void)out_size; (void)ws_size;
    const int N = N_NODES;
    const int E = N_EDGES;
    const int Etot = E + N;

    const float* x = (const float*)d_in[0];
    const int* ei = (const int*)d_in[1];
    const float* Wc[4] = {(const float*)d_in[3], (const float*)d_in[7],
                          (const float*)d_in[11], (const float*)d_in[15]};
    const float* AS[4] = {(const float*)d_in[4], (const float*)d_in[8],
                          (const float*)d_in[12], (const float*)d_in[16]};
    const float* AD[4] = {(const float*)d_in[5], (const float*)d_in[9],
                          (const float*)d_in[13], (const float*)d_in[17]};
    const float* Bc[4] = {(const float*)d_in[6], (const float*)d_in[10],
                          (const float*)d_in[14], (const float*)d_in[18]};
    const float* LW[4] = {(const float*)d_in[19], (const float*)d_in[21],
                          (const float*)d_in[23], (const float*)d_in[25]};
    const float* LB[4] = {(const float*)d_in[20], (const float*)d_in[22],
                          (const float*)d_in[24], (const float*)d_in[26]};

    char* w = (char*)d_ws;
    auto alloc = [&](size_t bytes) -> char* {
        char* p = w; w += (bytes + 255) & ~(size_t)255; return p;
    };
    unsigned short* bufC16 = (unsigned short*)alloc((size_t)N * 256 * 2); // GEMM out, fp16
    unsigned short* actHi = (unsigned short*)alloc((size_t)N * 256 * 2);
    unsigned short* actLo = (unsigned short*)alloc((size_t)N * 256 * 2);
    unsigned short* csr = (unsigned short*)alloc((size_t)Etot * 2);  // u16 src ids
    // alSD (4 layers x [alS|alD]) + counts/cursor: contiguous, single memset
    float* alSD = (float*)alloc((size_t)N * 4 * 4 * 4 + (size_t)N * 2 * 4);
    int* cnt2   = (int*)(alSD + (size_t)N * 16);
    int* counts = cnt2;
    int* cursor = cnt2 + N;
    int* indptr = (int*)alloc((size_t)(N + 8) * 4);
    int* bsum   = (int*)alloc(1024);
    int* boff   = (int*)alloc(1024);

    const int KpConv[4] = {352, 256, 160, 128};
    const int NpConv[4] = {256, 192, 128, 64};
    const int KpLin[4]  = {512, 224, 128, 128};
    const int NpLin[4]  = {256, 128, 128, 64};
    unsigned short *WtHi[4], *WtLo[4], *LtHi[4], *LtLo[4];
    for (int l = 0; l < 4; ++l) {
        WtHi[l] = (unsigned short*)alloc((size_t)NpConv[l] * KpConv[l] * 2);
        WtLo[l] = (unsigned short*)alloc((size_t)NpConv[l] * KpConv[l] * 2);
    }
    for (int l = 0; l < 4; ++l) {
        LtHi[l] = (unsigned short*)alloc((size_t)NpLin[l] * KpLin[l] * 2);
        LtLo[l] = (unsigned short*)alloc((size_t)NpLin[l] * KpLin[l] * 2);
    }

    const int* esrc = ei;
    const int* edst = ei + E;

    // ---- CSR by dst incl. self-loops; zero al buffers + counts in one memset ----
    hipMemsetAsync(alSD, 0, (size_t)N * 4 * 4 * 4 + (size_t)N * 2 * 4, stream);
    hist_self_k<<<(E + N) / 256, 256, 0, stream>>>(edst, E, counts, N);
    scan_block_k<<<N / 256, 256, 0, stream>>>(counts, indptr, bsum, N);
    scan_tops_k<<<1, 256, 0, stream>>>(bsum, boff);
    scan_add_k<<<N / 256, 256, 0, stream>>>(indptr, boff, N, Etot);
    fill_all_k<<<(E + N) / 256, 256, 0, stream>>>(esrc, edst, E, indptr, cursor, csr, N);

    // ---- weight decompose (one kernel for all 8) ----
    const int Kc[4] = {336, 250, 150, 100}, Nc[4] = {250, 150, 100, 60};
    const int Kl[4] = {480, 200, 100, 100}, Nl[4] = {200, 100, 100, 29};
    WtJobs jobs;
    int nb = 0;
    for (int l = 0; l < 4; ++l) {
        jobs.j[l] = {Wc[l], WtHi[l], WtLo[l], Kc[l], Nc[l], KpConv[l], 0, nb};
        nb += NpConv[l];
    }
    for (int l = 0; l < 4; ++l) {
        jobs.j[4 + l] = {LW[l], LtHi[l], LtLo[l], Kl[l], Nl[l], KpLin[l],
                         l == 0 ? 1 : 0, nb};
        nb += NpLin[l];
    }
    wt_decomp_all<<<nb, 256, 0, stream>>>(jobs);

    // ---- 4 GAT layers (stats fused into every gather; fp16 h) ----
    const int HCp[4]  = {256, 152, 100, 60};   // fp16 GEMM-out leading dim
    const int ldoA[4] = {256, 160, 128, 64};   // bf16 act leading dim (= next Kp)
    const int ldaA[4] = {336, 256, 160, 128};  // A leading dim into GEMM
    for (int l = 0; l < 4; ++l) {
        int C = Nc[l] / 2, HC = Nc[l];
        float* alS = alSD + (size_t)l * N * 4;
        float* alD = alS + (size_t)N * 2;
        if (l == 0) {
            gemm_mfma<128><<<dim3(2, N / 128), 256, 0, stream>>>(
                x, 336, nullptr, nullptr, 336, 352,
                WtHi[0], WtLo[0],
                bufC16, HCp[0], HCp[0],
                AS[0], AD[0], alS, alD, C, HC);
        } else if (l == 1) {
            gemm_mfma<64><<<dim3(3, N / 128), 256, 0, stream>>>(
                nullptr, 0, actHi, actLo, ldaA[1], KpConv[1],
                WtHi[1], WtLo[1],
                bufC16, HCp[1], HCp[1],
                AS[1], AD[1], alS, alD, C, HC);
        } else if (l == 2) {
            gemm_mfma<128><<<dim3(1, N / 128), 256, 0, stream>>>(
                nullptr, 0, actHi, actLo, ldaA[2], KpConv[2],
                WtHi[2], WtLo[2],
                bufC16, HCp[2], HCp[2],
                AS[2], AD[2], alS, alD, C, HC);
        } else {
            gemm_mfma<64><<<dim3(1, N / 128), 256, 0, stream>>>(
                nullptr, 0, actHi, actLo, ldaA[3], KpConv[3],
                WtHi[3], WtLo[3],
                bufC16, HCp[3], HCp[3],
                AS[3], AD[3], alS, alD, C, HC);
        }
        if (l == 0) {
            gat_gather_fused<64><<<N / 4, 256, 0, stream>>>(
                bufC16, alS, alD, indptr, csr, Bc[0],
                actHi, actLo, ldoA[0], N, C, HC, HCp[0]);
        } else if (l == 1) {
            gat_gather_fused<64><<<N / 4, 256, 0, stream>>>(
                bufC16, alS, alD, indptr, csr, Bc[1],
                actHi, actLo, ldoA[1], N, C, HC, HCp[1]);
        } else if (l == 2) {
            gat_gather_fused<32><<<N / 4, 256, 0, stream>>>(
                bufC16, alS, alD, indptr, csr, Bc[2],
                actHi, actLo, ldoA[2], N, C, HC, HCp[2]);
        } else {
            gat_gather_fused<16><<<N / 4, 256, 0, stream>>>(
                bufC16, alS, alD, indptr, csr, Bc[3],
                actHi, actLo, ldoA[3], N, C, HC, HCp[3]);
        }
    }

    // ---- MLP head, fused: [8192,480(512 remapped)] -> 200 -> 100 -> 100 -> 29 ----
    mlp_fused<<<8192 / 32, 256, 0, stream>>>(
        actHi, actLo,
        LtHi[0], LtLo[0], LtHi[1], LtLo[1],
        LtHi[2], LtLo[2], LtHi[3], LtLo[3],
        LB[0], LB[1], LB[2], LB[3],
        (float*)d_out);
}

// Round 6
// 813.316 us; speedup vs baseline: 1.8741x; 1.0313x over previous
//
#include <hip/hip_runtime.h>
#include <hip/hip_bf16.h>
#include <stdint.h>

#define N_NODES 65536
#define N_EDGES (N_NODES * 16)
#define NEG_SLOPE 0.2f

typedef short bf16x8 __attribute__((ext_vector_type(8)));   // 8 bf16 in 4 VGPRs
typedef float f32x4 __attribute__((ext_vector_type(4)));
typedef unsigned int u32x2 __attribute__((ext_vector_type(2)));
typedef _Float16 f16x4 __attribute__((ext_vector_type(4))); // 4 fp16 = 8B

__device__ __forceinline__ unsigned short f2bf(float f) {
    unsigned u = __float_as_uint(f);
    u += 0x7fffu + ((u >> 16) & 1u);       // RNE
    return (unsigned short)(u >> 16);
}
__device__ __forceinline__ float bf2f(unsigned short h) {
    return __uint_as_float(((unsigned)h) << 16);
}
__device__ __forceinline__ unsigned short f2h(float f) {
    _Float16 h = (_Float16)f;              // v_cvt_f16_f32, RNE
    union { _Float16 h; unsigned short u; } cv; cv.h = h; return cv.u;
}
__device__ __forceinline__ float rl_f(float v, int lane) {  // wave-uniform readlane
    return __int_as_float(__builtin_amdgcn_readlane(__float_as_int(v), lane));
}
__device__ __forceinline__ void load_lds16(const void* g, void* l) {
    __builtin_amdgcn_global_load_lds(
        (const __attribute__((address_space(1))) unsigned int*)g,
        (__attribute__((address_space(3))) unsigned int*)l, 16, 0, 0);
}
// nontemporal 8B store of a ushort4 (streaming output; keep L2 for gather rows)
__device__ __forceinline__ void nt_store_us4(unsigned short* p, ushort4 v) {
    u32x2 d;
    d.x = (unsigned)v.x | ((unsigned)v.y << 16);
    d.y = (unsigned)v.z | ((unsigned)v.w << 16);
    __builtin_nontemporal_store(d, (u32x2*)p);
}

// ---------------- MFMA GEMM: C[M,Nw] = A[M,Kp] @ Wt^T ----------------
// A: fp32 (A32 path, converted during staging) or bf16 hi/lo pair.
// Wt transposed [n][Kp] bf16 hi/lo, zero-padded.
// Split-bf16: acc += Ahi*Bhi + Alo*Bhi + Ahi*Blo  (fp32 MFMA accumulate).
// C output: fp16 (RNE) — gather input; halves gather fill traffic vs fp32.
// If asrc != null: also computes per-row attention dots al_s/al_d in FP32
// (atomicAdd) — softmax weights therefore unchanged vs the fp32-C version.
template<int TN>
__global__ __launch_bounds__(256) void gemm_mfma(
    const float* __restrict__ A32, int KA,
    const unsigned short* __restrict__ Ahi, const unsigned short* __restrict__ Alo,
    int lda, int Kp,
    const unsigned short* __restrict__ Bhi, const unsigned short* __restrict__ Blo,
    unsigned short* __restrict__ C16,
    int ldc, int Nw,
    const float* __restrict__ asrc, const float* __restrict__ adst,
    float* __restrict__ alS, float* __restrict__ alD, int Cal, int HCal)
{
    constexpr int NI = TN / 32;                 // N-frags per wave
    __shared__ unsigned short sAhi[128 * 32], sAlo[128 * 32];
    __shared__ unsigned short sBhi[TN * 32],  sBlo[TN * 32];
    __shared__ float sAl[128][2][4];
    const int tid = threadIdx.x;
    const int wave = tid >> 6, lane = tid & 63;
    const int row0 = blockIdx.y * 128;
    const int col0 = blockIdx.x * TN;
    const int wm = (wave & 1) * 64, wn = (wave >> 1) * (TN / 2);
    const int mlane = lane & 15, q = lane >> 4;

    f32x4 acc[4][NI];
#pragma unroll
    for (int a = 0; a < 4; ++a)
#pragma unroll
        for (int b = 0; b < NI; ++b) acc[a][b] = (f32x4){0.f, 0.f, 0.f, 0.f};

    for (int k0 = 0; k0 < Kp; k0 += 32) {
        __syncthreads();
        if (A32) {
            // fp32 -> bf16 hi/lo conversion staging (layer 1 only)
            const int r = tid >> 1, cbase = (tid & 1) * 16;
            const float* Ap = A32 + (size_t)(row0 + r) * lda;
#pragma unroll
            for (int j = 0; j < 4; ++j) {
                int kc = k0 + cbase + j * 4;
                float4 v = make_float4(0.f, 0.f, 0.f, 0.f);
                if (kc < KA) v = *(const float4*)(Ap + kc);
                ushort4 h, l;
                h.x = f2bf(v.x); l.x = f2bf(v.x - bf2f(h.x));
                h.y = f2bf(v.y); l.y = f2bf(v.y - bf2f(h.y));
                h.z = f2bf(v.z); l.z = f2bf(v.z - bf2f(h.z));
                h.w = f2bf(v.w); l.w = f2bf(v.w - bf2f(h.w));
                *(ushort4*)(sAhi + r * 32 + cbase + j * 4) = h;
                *(ushort4*)(sAlo + r * 32 + cbase + j * 4) = l;
            }
        } else {
            // async global->LDS, 16B/lane; LDS dst = wave-uniform base + lane*16
#pragma unroll
            for (int cc = 0; cc < 2; ++cc) {
                int c = wave * 2 + cc;                 // 8 chunks of 16 rows
                int r = c * 16 + (lane >> 2);
                size_t goff = (size_t)(row0 + r) * lda + k0 + (lane & 3) * 8;
                load_lds16(Ahi + goff, sAhi + c * 512);
                load_lds16(Alo + goff, sAlo + c * 512);
            }
        }
        {
#pragma unroll
            for (int cc = 0; cc < TN / 64; ++cc) {
                int c = wave * (TN / 64) + cc;         // TN/16 chunks of 16 rows
                int r = c * 16 + (lane >> 2);
                size_t goff = (size_t)(col0 + r) * Kp + k0 + (lane & 3) * 8;
                load_lds16(Bhi + goff, sBhi + c * 512);
                load_lds16(Blo + goff, sBlo + c * 512);
            }
        }
        __syncthreads();

        bf16x8 ah[4], al[4], bh[NI], bl[NI];
#pragma unroll
        for (int mi = 0; mi < 4; ++mi) {
            int m = wm + mi * 16 + mlane;
            ah[mi] = *(const bf16x8*)(sAhi + m * 32 + q * 8);
            al[mi] = *(const bf16x8*)(sAlo + m * 32 + q * 8);
        }
#pragma unroll
        for (int ni = 0; ni < NI; ++ni) {
            int n = wn + ni * 16 + mlane;
            bh[ni] = *(const bf16x8*)(sBhi + n * 32 + q * 8);
            bl[ni] = *(const bf16x8*)(sBlo + n * 32 + q * 8);
        }
#pragma unroll
        for (int mi = 0; mi < 4; ++mi)
#pragma unroll
            for (int ni = 0; ni < NI; ++ni) {
                acc[mi][ni] = __builtin_amdgcn_mfma_f32_16x16x32_bf16(ah[mi], bh[ni], acc[mi][ni], 0, 0, 0);
                acc[mi][ni] = __builtin_amdgcn_mfma_f32_16x16x32_bf16(al[mi], bh[ni], acc[mi][ni], 0, 0, 0);
                acc[mi][ni] = __builtin_amdgcn_mfma_f32_16x16x32_bf16(ah[mi], bl[ni], acc[mi][ni], 0, 0, 0);
            }
    }

    // epilogue: C/D frag layout col=lane&15, row=(lane>>4)*4+reg; fp16 store
#pragma unroll
    for (int ni = 0; ni < NI; ++ni) {
        int col = col0 + wn + ni * 16 + mlane;
        if (col >= Nw) continue;
#pragma unroll
        for (int mi = 0; mi < 4; ++mi) {
#pragma unroll
            for (int reg = 0; reg < 4; ++reg) {
                int row = row0 + wm + mi * 16 + q * 4 + reg;
                C16[(size_t)row * ldc + col] = f2h(acc[mi][ni][reg]);
            }
        }
    }

    // fused attention-logit dots: al_s[row,h] += sum_c h[row,c]*a_s[h,c], same for a_d
    if (asrc) {
        float asv[NI], adv[NI];
        bool head0[NI];
#pragma unroll
        for (int ni = 0; ni < NI; ++ni) {
            int col = col0 + wn + ni * 16 + mlane;
            bool valid = col < HCal;
            head0[ni] = col < Cal;
            asv[ni] = valid ? asrc[col] : 0.f;
            adv[ni] = valid ? adst[col] : 0.f;
        }
#pragma unroll
        for (int mi = 0; mi < 4; ++mi) {
#pragma unroll
            for (int reg = 0; reg < 4; ++reg) {
                float s0 = 0.f, s1 = 0.f, d0 = 0.f, d1 = 0.f;
#pragma unroll
                for (int ni = 0; ni < NI; ++ni) {
                    float v = acc[mi][ni][reg];
                    if (head0[ni]) { s0 += v * asv[ni]; d0 += v * adv[ni]; }
                    else           { s1 += v * asv[ni]; d1 += v * adv[ni]; }
                }
#pragma unroll
                for (int off = 1; off < 16; off <<= 1) {
                    s0 += __shfl_xor(s0, off); s1 += __shfl_xor(s1, off);
                    d0 += __shfl_xor(d0, off); d1 += __shfl_xor(d1, off);
                }
                if (mlane == 0) {
                    int rl = wm + mi * 16 + q * 4 + reg;
                    int slot = wave >> 1;
                    sAl[rl][slot][0] = s0; sAl[rl][slot][1] = s1;
                    sAl[rl][slot][2] = d0; sAl[rl][slot][3] = d1;
                }
            }
        }
        __syncthreads();
        if (tid < 128) {
            int row = row0 + tid;
            float v0 = sAl[tid][0][0] + sAl[tid][1][0];
            float v1 = sAl[tid][0][1] + sAl[tid][1][1];
            float v2 = sAl[tid][0][2] + sAl[tid][1][2];
            float v3 = sAl[tid][0][3] + sAl[tid][1][3];
            atomicAdd(&alS[row * 2 + 0], v0);
            atomicAdd(&alS[row * 2 + 1], v1);
            atomicAdd(&alD[row * 2 + 0], v2);
            atomicAdd(&alD[row * 2 + 1], v3);
        }
    }
}

// ------------- fused MLP head: 4 layers in one kernel, 32 rows/block -------------
template<int NI>
__device__ __forceinline__ void mlp_layer(
    const unsigned short* aHi, const unsigned short* aLo, int ldaS, int K,
    const unsigned short* __restrict__ Bhi, const unsigned short* __restrict__ Blo,
    int Kp,
    unsigned short* sBh, unsigned short* sBl,
    const float* __restrict__ bias, int Nbias, int colBase,
    unsigned short* oHi, unsigned short* oLo, int ldo, int Nstore,
    float* __restrict__ gOut, int row0, int relu,
    int wave, int lane)
{
    const int mlane = lane & 15, q = lane >> 4;
    const int wm = (wave & 1) * 16;
    const int wn = (wave >> 1) * (NI * 16);
    f32x4 acc[NI];
#pragma unroll
    for (int b = 0; b < NI; ++b) acc[b] = (f32x4){0.f, 0.f, 0.f, 0.f};

    for (int k0 = 0; k0 < K; k0 += 32) {
        __syncthreads();
        for (int c = wave; c < NI * 2; c += 4) {   // stage B rows (N = NI*32)
            int r = c * 16 + (lane >> 2);
            size_t goff = (size_t)r * Kp + k0 + (lane & 3) * 8;
            load_lds16(Bhi + goff, sBh + c * 512);
            load_lds16(Blo + goff, sBl + c * 512);
        }
        __syncthreads();

        bf16x8 ah, al, bh[NI], bl[NI];
        ah = *(const bf16x8*)(aHi + (wm + mlane) * ldaS + k0 + q * 8);
        al = *(const bf16x8*)(aLo + (wm + mlane) * ldaS + k0 + q * 8);
#pragma unroll
        for (int ni = 0; ni < NI; ++ni) {
            int n = wn + ni * 16 + mlane;
            bh[ni] = *(const bf16x8*)(sBh + n * 32 + q * 8);
            bl[ni] = *(const bf16x8*)(sBl + n * 32 + q * 8);
        }
#pragma unroll
        for (int ni = 0; ni < NI; ++ni) {
            acc[ni] = __builtin_amdgcn_mfma_f32_16x16x32_bf16(ah, bh[ni], acc[ni], 0, 0, 0);
            acc[ni] = __builtin_amdgcn_mfma_f32_16x16x32_bf16(al, bh[ni], acc[ni], 0, 0, 0);
            acc[ni] = __builtin_amdgcn_mfma_f32_16x16x32_bf16(ah, bl[ni], acc[ni], 0, 0, 0);
        }
    }
    __syncthreads();   // all reads of aHi/aLo done before caller overwrites

#pragma unroll
    for (int ni = 0; ni < NI; ++ni) {
        int colg = colBase + wn + ni * 16 + mlane;
        float bv = (colg < Nbias) ? bias[colg] : 0.f;
#pragma unroll
        for (int reg = 0; reg < 4; ++reg) {
            int row = wm + q * 4 + reg;
            float v = acc[ni][reg] + bv;
            if (relu) v = fmaxf(v, 0.f);
            if (gOut) {
                if (colg < 29) gOut[(size_t)(row0 + row) * 29 + colg] = v;
            } else if (colg < Nstore) {
                unsigned short h = f2bf(v);
                oHi[row * ldo + colg] = h;
                oLo[row * ldo + colg] = f2bf(v - bf2f(h));
            }
        }
    }
}

__global__ __launch_bounds__(256) void mlp_fused(
    const unsigned short* __restrict__ actHi, const unsigned short* __restrict__ actLo,
    const unsigned short* __restrict__ L1h, const unsigned short* __restrict__ L1l,
    const unsigned short* __restrict__ L2h, const unsigned short* __restrict__ L2l,
    const unsigned short* __restrict__ L3h, const unsigned short* __restrict__ L3l,
    const unsigned short* __restrict__ L4h, const unsigned short* __restrict__ L4l,
    const float* __restrict__ B1, const float* __restrict__ B2,
    const float* __restrict__ B3, const float* __restrict__ B4,
    float* __restrict__ out)
{
    __shared__ unsigned short b1h[32 * 224], b1l[32 * 224];   // L1 out / L3 out
    __shared__ unsigned short b2h[32 * 128], b2l[32 * 128];   // L2 out
    __shared__ unsigned short sAh[32 * 32],  sAl[32 * 32];    // L1 A staging
    __shared__ unsigned short sBh[128 * 32], sBl[128 * 32];   // B staging
    const int tid = threadIdx.x;
    const int wave = tid >> 6, lane = tid & 63;
    const int row0 = blockIdx.x * 32;
    const int mlane = lane & 15, q = lane >> 4;
    const int wm = (wave & 1) * 16;
    const int wn = (wave >> 1) * 64;

    // ---- layer 1: [32,512] @ L1^T -> b1 [32,224], two 128-col tiles ----
    for (int nt = 0; nt < 2; ++nt) {
        const unsigned short* Bh = L1h + (size_t)nt * 128 * 512;
        const unsigned short* Bl = L1l + (size_t)nt * 128 * 512;
        f32x4 acc[4];
#pragma unroll
        for (int b = 0; b < 4; ++b) acc[b] = (f32x4){0.f, 0.f, 0.f, 0.f};
        for (int k0 = 0; k0 < 512; k0 += 32) {
            __syncthreads();
            for (int c = wave; c < 2; c += 4) {      // A: 32 rows
                int r = c * 16 + (lane >> 2);
                size_t goff = (size_t)(row0 + r) * 512 + k0 + (lane & 3) * 8;
                load_lds16(actHi + goff, sAh + c * 512);
                load_lds16(actLo + goff, sAl + c * 512);
            }
            for (int c = wave; c < 8; c += 4) {      // B: 128 rows
                int r = c * 16 + (lane >> 2);
                size_t goff = (size_t)r * 512 + k0 + (lane & 3) * 8;
                load_lds16(Bh + goff, sBh + c * 512);
                load_lds16(Bl + goff, sBl + c * 512);
            }
            __syncthreads();
            bf16x8 ah = *(const bf16x8*)(sAh + (wm + mlane) * 32 + q * 8);
            bf16x8 al = *(const bf16x8*)(sAl + (wm + mlane) * 32 + q * 8);
#pragma unroll
            for (int ni = 0; ni < 4; ++ni) {
                int n = wn + ni * 16 + mlane;
                bf16x8 bh = *(const bf16x8*)(sBh + n * 32 + q * 8);
                bf16x8 bl = *(const bf16x8*)(sBl + n * 32 + q * 8);
                acc[ni] = __builtin_amdgcn_mfma_f32_16x16x32_bf16(ah, bh, acc[ni], 0, 0, 0);
                acc[ni] = __builtin_amdgcn_mfma_f32_16x16x32_bf16(al, bh, acc[ni], 0, 0, 0);
                acc[ni] = __builtin_amdgcn_mfma_f32_16x16x32_bf16(ah, bl, acc[ni], 0, 0, 0);
            }
        }
        __syncthreads();
#pragma unroll
        for (int ni = 0; ni < 4; ++ni) {
            int colg = nt * 128 + wn + ni * 16 + mlane;
            float bv = (colg < 200) ? B1[colg] : 0.f;
#pragma unroll
            for (int reg = 0; reg < 4; ++reg) {
                int row = wm + q * 4 + reg;
                float v = fmaxf(acc[ni][reg] + bv, 0.f);
                if (colg < 224) {
                    unsigned short h = f2bf(v);
                    b1h[row * 224 + colg] = h;
                    b1l[row * 224 + colg] = f2bf(v - bf2f(h));
                }
            }
        }
    }
    __syncthreads();

    // ---- layer 2: b1[32,224] -> b2[32,128] ----
    mlp_layer<4>(b1h, b1l, 224, 224, L2h, L2l, 224, sBh, sBl,
                 B2, 100, 0, b2h, b2l, 128, 128, nullptr, 0, 1, wave, lane);
    __syncthreads();
    // ---- layer 3: b2[32,128] -> b1[32,128] (reuse, ld 128) ----
    mlp_layer<4>(b2h, b2l, 128, 128, L3h, L3l, 128, sBh, sBl,
                 B3, 100, 0, b1h, b1l, 128, 128, nullptr, 0, 1, wave, lane);
    __syncthreads();
    // ---- layer 4: b1[32,128] -> out[32,29] fp32 ----
    mlp_layer<2>(b1h, b1l, 128, 128, L4h, L4l, 128, sBh, sBl,
                 B4, 29, 0, nullptr, nullptr, 0, 0, out, row0, 0, wave, lane);
}

// ---------------- weight transpose + bf16 hi/lo decompose (all 8 in one) ----------
struct WtJob {
    const float* W; unsigned short* Whi; unsigned short* Wlo;
    int K, N, Kp, remap, nb0;
};
struct WtJobs { WtJob j[8]; };

__global__ void wt_decomp_all(WtJobs jobs)
{
    int b = blockIdx.x;
    int idx = 0;
#pragma unroll
    for (int i = 1; i < 8; ++i)
        if (b >= jobs.j[i].nb0) idx = i;
    WtJob jb = jobs.j[idx];
    int n = b - jb.nb0;
    for (int k = threadIdx.x; k < jb.Kp; k += 256) {
        int ks = k, valid = 1;
        if (jb.remap) {
            int bb = k >> 6, r = k & 63;
            if (r < 60) ks = bb * 60 + r; else valid = 0;
        }
        float v = 0.f;
        if (valid && ks < jb.K && n < jb.N) v = jb.W[(size_t)ks * jb.N + n];
        unsigned short h = f2bf(v);
        jb.Whi[(size_t)n * jb.Kp + k] = h;
        jb.Wlo[(size_t)n * jb.Kp + k] = f2bf(v - bf2f(h));
    }
}

// ------- fused stats+gather (all 4 layers, one wave per node) -------
// deg<=64 fast path (virtually all nodes): chunk-0 lanes each own one edge;
// e is computed ONCE and cached in registers. max via fmax butterfly; den via
// butterfly-sum of exp(e-m) — that exp IS the weight numerator (reused), so
// no separate weight pre-pass. Weights = same softmax, den FP-reassociated
// (~1 ulp) vs the online-merge order; h is fp16.
// G==1 (LPE=64): broadcast index u is wave-uniform -> v_readlane (no LDS pipe),
// and s becomes scalar (scalar address math on the h-row load).
// deg>64 fallback: the round-5 online-stats + chunked-shfl path, unchanged.
template<int LPE>
__global__ __launch_bounds__(256) void gat_gather_fused(
    const unsigned short* __restrict__ h16,
    const float* __restrict__ al_s, const float* __restrict__ al_d,
    const int* __restrict__ indptr, const unsigned short* __restrict__ csr_src,
    const float* __restrict__ bias,
    unsigned short* __restrict__ outHi, unsigned short* __restrict__ outLo,
    int ldo, int Nn, int C, int HC, int HCpad)
{
    constexpr int G = 64 / LPE;
    const int wave = threadIdx.x >> 6, lane = threadIdx.x & 63;
    const int i = blockIdx.x * 4 + wave;
    if (i >= Nn) return;
    const int start = indptr[i], end = indptr[i + 1];
    const int deg = end - start;
    const float ad0 = al_d[2 * i], ad1 = al_d[2 * i + 1];

    const int l = lane % LPE;
    const int g = lane / LPE;
    const int ch4 = l * 4;
    const bool chA = ch4 < HCpad;
    const bool c0 = (ch4 + 0) < C, c1 = (ch4 + 1) < C,
               c2 = (ch4 + 2) < C, c3 = (ch4 + 3) < C;
    float a0 = 0.f, a1 = 0.f, a2 = 0.f, a3 = 0.f;

    if (deg <= 64) {
        // ---------------- fast path ----------------
        const int jW = start + lane;
        const bool have = jW < end;
        int ps = 0;
        float e0r = 0.f, e1r = 0.f;
        if (have) {
            ps = csr_src[jW];
            float2 as = *(const float2*)(al_s + 2 * ps);
            e0r = as.x + ad0; e0r = e0r > 0.f ? e0r : NEG_SLOPE * e0r;
            e1r = as.y + ad1; e1r = e1r > 0.f ? e1r : NEG_SLOPE * e1r;
        }
        // max butterfly
        float m0 = have ? e0r : -1e30f;
        float m1 = have ? e1r : -1e30f;
#pragma unroll
        for (int off = 32; off; off >>= 1) {
            m0 = fmaxf(m0, __shfl_xor(m0, off));
            m1 = fmaxf(m1, __shfl_xor(m1, off));
        }
        // numerators (double as weights)
        float n0 = have ? __expf(e0r - m0) : 0.f;
        float n1 = have ? __expf(e1r - m1) : 0.f;
        // den butterfly-sum
        float den0 = n0, den1 = n1;
#pragma unroll
        for (int off = 32; off; off >>= 1) {
            den0 += __shfl_xor(den0, off);
            den1 += __shfl_xor(den1, off);
        }
        const float pw0 = n0 * (1.f / den0);
        const float pw1 = n1 * (1.f / den1);

        if constexpr (G == 1) {
            for (int u = 0; u < deg; ++u) {
                float w0 = rl_f(pw0, u);
                float w1 = rl_f(pw1, u);
                int s = __builtin_amdgcn_readlane(ps, u);
                float hx = 0.f, hy = 0.f, hz = 0.f, hw = 0.f;
                if (chA) {
                    f16x4 hv = *(const f16x4*)(h16 + (size_t)s * HCpad + ch4);
                    hx = (float)hv[0]; hy = (float)hv[1];
                    hz = (float)hv[2]; hw = (float)hv[3];
                }
                a0 = fmaf(c0 ? w0 : w1, hx, a0);
                a1 = fmaf(c1 ? w0 : w1, hy, a1);
                a2 = fmaf(c2 ? w0 : w1, hz, a2);
                a3 = fmaf(c3 ? w0 : w1, hw, a3);
            }
        } else {
            const int nit = (deg + G - 1) / G;
            for (int u = 0; u < nit; ++u) {
                int idx = u * G + g;               // < 64; lanes>=deg hold w=0
                float w0 = __shfl(pw0, idx);
                float w1 = __shfl(pw1, idx);
                int s = __shfl(ps, idx);
                float hx = 0.f, hy = 0.f, hz = 0.f, hw = 0.f;
                if (chA) {
                    f16x4 hv = *(const f16x4*)(h16 + (size_t)s * HCpad + ch4);
                    hx = (float)hv[0]; hy = (float)hv[1];
                    hz = (float)hv[2]; hw = (float)hv[3];
                }
                a0 = fmaf(c0 ? w0 : w1, hx, a0);
                a1 = fmaf(c1 ? w0 : w1, hy, a1);
                a2 = fmaf(c2 ? w0 : w1, hz, a2);
                a3 = fmaf(c3 ? w0 : w1, hw, a3);
            }
        }
    } else {
        // ---------------- fallback: round-5 online path (rare) ----------------
        float m0 = -1e30f, m1 = -1e30f, den0 = 0.f, den1 = 0.f;
        for (int j = start + lane; j < end; j += 64) {
            int s = csr_src[j];
            float2 as = *(const float2*)(al_s + 2 * s);
            float e0 = as.x + ad0; e0 = e0 > 0.f ? e0 : NEG_SLOPE * e0;
            float e1 = as.y + ad1; e1 = e1 > 0.f ? e1 : NEG_SLOPE * e1;
            float n0 = fmaxf(m0, e0);
            den0 = den0 * __expf(m0 - n0) + __expf(e0 - n0);
            m0 = n0;
            float n1 = fmaxf(m1, e1);
            den1 = den1 * __expf(m1 - n1) + __expf(e1 - n1);
            m1 = n1;
        }
#pragma unroll
        for (int off = 32; off; off >>= 1) {
            float mo0 = __shfl_xor(m0, off), do0 = __shfl_xor(den0, off);
            float n0 = fmaxf(m0, mo0);
            den0 = den0 * __expf(m0 - n0) + do0 * __expf(mo0 - n0);
            m0 = n0;
            float mo1 = __shfl_xor(m1, off), do1 = __shfl_xor(den1, off);
            float n1 = fmaxf(m1, mo1);
            den1 = den1 * __expf(m1 - n1) + do1 * __expf(mo1 - n1);
            m1 = n1;
        }
        const float inv0 = 1.f / den0, inv1 = 1.f / den1;

        for (int jb = start; jb < end; jb += 64) {
            int jW = jb + lane;
            float pw0 = 0.f, pw1 = 0.f;
            int ps = 0;
            if (jW < end) {
                ps = csr_src[jW];
                float2 as = *(const float2*)(al_s + 2 * ps);
                float e0 = as.x + ad0; e0 = e0 > 0.f ? e0 : NEG_SLOPE * e0;
                float e1 = as.y + ad1; e1 = e1 > 0.f ? e1 : NEG_SLOPE * e1;
                pw0 = __expf(e0 - m0) * inv0;
                pw1 = __expf(e1 - m1) * inv1;
            }
            int nedge = end - jb; if (nedge > 64) nedge = 64;
            int nit = (nedge + G - 1) / G;
            for (int u = 0; u < nit; ++u) {
                int idx = u * G + g;
                float w0 = __shfl(pw0, idx);
                float w1 = __shfl(pw1, idx);
                int s = __shfl(ps, idx);
                float hx = 0.f, hy = 0.f, hz = 0.f, hw = 0.f;
                if (chA) {
                    f16x4 hv = *(const f16x4*)(h16 + (size_t)s * HCpad + ch4);
                    hx = (float)hv[0]; hy = (float)hv[1];
                    hz = (float)hv[2]; hw = (float)hv[3];
                }
                a0 = fmaf(c0 ? w0 : w1, hx, a0);
                a1 = fmaf(c1 ? w0 : w1, hy, a1);
                a2 = fmaf(c2 ? w0 : w1, hz, a2);
                a3 = fmaf(c3 ? w0 : w1, hw, a3);
            }
        }
    }

    // ---- shared tail: cross-group reduce, bias+relu, bf16 hi/lo store ----
#pragma unroll
    for (int off = LPE; off < 64; off <<= 1) {
        a0 += __shfl_xor(a0, off);
        a1 += __shfl_xor(a1, off);
        a2 += __shfl_xor(a2, off);
        a3 += __shfl_xor(a3, off);
    }
    if (g == 0 && chA) {
        float bx = (ch4 + 0 < HC) ? bias[ch4 + 0] : 0.f;
        float by = (ch4 + 1 < HC) ? bias[ch4 + 1] : 0.f;
        float bz = (ch4 + 2 < HC) ? bias[ch4 + 2] : 0.f;
        float bw = (ch4 + 3 < HC) ? bias[ch4 + 3] : 0.f;
        float v0 = fmaxf(a0 + bx, 0.f);
        float v1 = fmaxf(a1 + by, 0.f);
        float v2 = fmaxf(a2 + bz, 0.f);
        float v3 = fmaxf(a3 + bw, 0.f);
        ushort4 h, lo;
        h.x = f2bf(v0); lo.x = f2bf(v0 - bf2f(h.x));
        h.y = f2bf(v1); lo.y = f2bf(v1 - bf2f(h.y));
        h.z = f2bf(v2); lo.z = f2bf(v2 - bf2f(h.z));
        h.w = f2bf(v3); lo.w = f2bf(v3 - bf2f(h.w));
        nt_store_us4(outHi + (size_t)i * ldo + ch4, h);
        nt_store_us4(outLo + (size_t)i * ldo + ch4, lo);
    }
    for (int z = HCpad + lane * 4; z < ldo; z += 256) {
        ushort4 zz; zz.x = zz.y = zz.z = zz.w = 0;
        *(ushort4*)(outHi + (size_t)i * ldo + z) = zz;
        *(ushort4*)(outLo + (size_t)i * ldo + z) = zz;
    }
}

// ---------------- CSR build (with self-loops folded in) ----------------
__global__ void hist_self_k(const int* __restrict__ dst, int E,
                            int* __restrict__ counts, int n)
{
    int gid = blockIdx.x * blockDim.x + threadIdx.x;
    if (gid < E) atomicAdd(&counts[dst[gid]], 1);
    else if (gid < E + n) atomicAdd(&counts[gid - E], 1);
}

__global__ void scan_block_k(const int* __restrict__ in, int* __restrict__ out,
                             int* __restrict__ bsum, int n)
{
    __shared__ int sh[256];
    int gid = blockIdx.x * 256 + threadIdx.x;
    int v = (gid < n) ? in[gid] : 0;
    sh[threadIdx.x] = v;
    __syncthreads();
    for (int off = 1; off < 256; off <<= 1) {
        int t = (threadIdx.x >= off) ? sh[threadIdx.x - off] : 0;
        __syncthreads();
        sh[threadIdx.x] += t;
        __syncthreads();
    }
    int incl = sh[threadIdx.x];
    if (gid < n) out[gid] = incl - v;
    if (threadIdx.x == 255) bsum[blockIdx.x] = incl;
}

__global__ void scan_tops_k(const int* __restrict__ bsum, int* __restrict__ boff)
{
    __shared__ int sh[256];
    int v = bsum[threadIdx.x];
    sh[threadIdx.x] = v;
    __syncthreads();
    for (int off = 1; off < 256; off <<= 1) {
        int t = (threadIdx.x >= off) ? sh[threadIdx.x - off] : 0;
        __syncthreads();
        sh[threadIdx.x] += t;
        __syncthreads();
    }
    boff[threadIdx.x] = sh[threadIdx.x] - v;
}

__global__ void scan_add_k(int* __restrict__ indptr, const int* __restrict__ boff,
                           int n, int Etot)
{
    int gid = blockIdx.x * 256 + threadIdx.x;
    if (gid < n) indptr[gid] += boff[blockIdx.x];
    if (gid == 0) indptr[n] = Etot;
}

__global__ void fill_all_k(const int* __restrict__ src, const int* __restrict__ dst,
                           int E, const int* __restrict__ indptr,
                           int* __restrict__ cursor,
                           unsigned short* __restrict__ csr_src, int n)
{
    int gid = blockIdx.x * blockDim.x + threadIdx.x;
    if (gid < E) {
        int d = dst[gid];
        int pos = atomicAdd(&cursor[d], 1);
        csr_src[indptr[d] + pos] = (unsigned short)src[gid];
    } else if (gid < E + n) {
        int i = gid - E;
        int pos = atomicAdd(&cursor[i], 1);
        csr_src[indptr[i] + pos] = (unsigned short)i;
    }
}

// ---------------- launch ----------------
extern "C" void kernel_launch(void* const* d_in, const int* in_sizes, int n_in,
                              void* d_out, int out_size, void* d_ws, size_t ws_size,
                              hipStream_t stream)
{
    (void)in_sizes; (void)n_in; (void)out_size; (void)ws_size;
    const int N = N_NODES;
    const int E = N_EDGES;
    const int Etot = E + N;

    const float* x = (const float*)d_in[0];
    const int* ei = (const int*)d_in[1];
    const float* Wc[4] = {(const float*)d_in[3], (const float*)d_in[7],
                          (const float*)d_in[11], (const float*)d_in[15]};
    const float* AS[4] = {(const float*)d_in[4], (const float*)d_in[8],
                          (const float*)d_in[12], (const float*)d_in[16]};
    const float* AD[4] = {(const float*)d_in[5], (const float*)d_in[9],
                          (const float*)d_in[13], (const float*)d_in[17]};
    const float* Bc[4] = {(const float*)d_in[6], (const float*)d_in[10],
                          (const float*)d_in[14], (const float*)d_in[18]};
    const float* LW[4] = {(const float*)d_in[19], (const float*)d_in[21],
                          (const float*)d_in[23], (const float*)d_in[25]};
    const float* LB[4] = {(const float*)d_in[20], (const float*)d_in[22],
                          (const float*)d_in[24], (const float*)d_in[26]};

    char* w = (char*)d_ws;
    auto alloc = [&](size_t bytes) -> char* {
        char* p = w; w += (bytes + 255) & ~(size_t)255; return p;
    };
    unsigned short* bufC16 = (unsigned short*)alloc((size_t)N * 256 * 2); // GEMM out, fp16
    unsigned short* actHi = (unsigned short*)alloc((size_t)N * 256 * 2);
    unsigned short* actLo = (unsigned short*)alloc((size_t)N * 256 * 2);
    unsigned short* csr = (unsigned short*)alloc((size_t)Etot * 2);  // u16 src ids
    // alSD (4 layers x [alS|alD]) + counts/cursor: contiguous, single memset
    float* alSD = (float*)alloc((size_t)N * 4 * 4 * 4 + (size_t)N * 2 * 4);
    int* cnt2   = (int*)(alSD + (size_t)N * 16);
    int* counts = cnt2;
    int* cursor = cnt2 + N;
    int* indptr = (int*)alloc((size_t)(N + 8) * 4);
    int* bsum   = (int*)alloc(1024);
    int* boff   = (int*)alloc(1024);

    const int KpConv[4] = {352, 256, 160, 128};
    const int NpConv[4] = {256, 192, 128, 64};
    const int KpLin[4]  = {512, 224, 128, 128};
    const int NpLin[4]  = {256, 128, 128, 64};
    unsigned short *WtHi[4], *WtLo[4], *LtHi[4], *LtLo[4];
    for (int l = 0; l < 4; ++l) {
        WtHi[l] = (unsigned short*)alloc((size_t)NpConv[l] * KpConv[l] * 2);
        WtLo[l] = (unsigned short*)alloc((size_t)NpConv[l] * KpConv[l] * 2);
    }
    for (int l = 0; l < 4; ++l) {
        LtHi[l] = (unsigned short*)alloc((size_t)NpLin[l] * KpLin[l] * 2);
        LtLo[l] = (unsigned short*)alloc((size_t)NpLin[l] * KpLin[l] * 2);
    }

    const int* esrc = ei;
    const int* edst = ei + E;

    // ---- CSR by dst incl. self-loops; zero al buffers + counts in one memset ----
    hipMemsetAsync(alSD, 0, (size_t)N * 4 * 4 * 4 + (size_t)N * 2 * 4, stream);
    hist_self_k<<<(E + N) / 256, 256, 0, stream>>>(edst, E, counts, N);
    scan_block_k<<<N / 256, 256, 0, stream>>>(counts, indptr, bsum, N);
    scan_tops_k<<<1, 256, 0, stream>>>(bsum, boff);
    scan_add_k<<<N / 256, 256, 0, stream>>>(indptr, boff, N, Etot);
    fill_all_k<<<(E + N) / 256, 256, 0, stream>>>(esrc, edst, E, indptr, cursor, csr, N);

    // ---- weight decompose (one kernel for all 8) ----
    const int Kc[4] = {336, 250, 150, 100}, Nc[4] = {250, 150, 100, 60};
    const int Kl[4] = {480, 200, 100, 100}, Nl[4] = {200, 100, 100, 29};
    WtJobs jobs;
    int nb = 0;
    for (int l = 0; l < 4; ++l) {
        jobs.j[l] = {Wc[l], WtHi[l], WtLo[l], Kc[l], Nc[l], KpConv[l], 0, nb};
        nb += NpConv[l];
    }
    for (int l = 0; l < 4; ++l) {
        jobs.j[4 + l] = {LW[l], LtHi[l], LtLo[l], Kl[l], Nl[l], KpLin[l],
                         l == 0 ? 1 : 0, nb};
        nb += NpLin[l];
    }
    wt_decomp_all<<<nb, 256, 0, stream>>>(jobs);

    // ---- 4 GAT layers (stats fused into every gather; fp16 h) ----
    const int HCp[4]  = {256, 152, 100, 60};   // fp16 GEMM-out leading dim
    const int ldoA[4] = {256, 160, 128, 64};   // bf16 act leading dim (= next Kp)
    const int ldaA[4] = {336, 256, 160, 128};  // A leading dim into GEMM
    for (int l = 0; l < 4; ++l) {
        int C = Nc[l] / 2, HC = Nc[l];
        float* alS = alSD + (size_t)l * N * 4;
        float* alD = alS + (size_t)N * 2;
        if (l == 0) {
            gemm_mfma<128><<<dim3(2, N / 128), 256, 0, stream>>>(
                x, 336, nullptr, nullptr, 336, 352,
                WtHi[0], WtLo[0],
                bufC16, HCp[0], HCp[0],
                AS[0], AD[0], alS, alD, C, HC);
        } else if (l == 1) {
            gemm_mfma<64><<<dim3(3, N / 128), 256, 0, stream>>>(
                nullptr, 0, actHi, actLo, ldaA[1], KpConv[1],
                WtHi[1], WtLo[1],
                bufC16, HCp[1], HCp[1],
                AS[1], AD[1], alS, alD, C, HC);
        } else if (l == 2) {
            gemm_mfma<128><<<dim3(1, N / 128), 256, 0, stream>>>(
                nullptr, 0, actHi, actLo, ldaA[2], KpConv[2],
                WtHi[2], WtLo[2],
                bufC16, HCp[2], HCp[2],
                AS[2], AD[2], alS, alD, C, HC);
        } else {
            gemm_mfma<64><<<dim3(1, N / 128), 256, 0, stream>>>(
                nullptr, 0, actHi, actLo, ldaA[3], KpConv[3],
                WtHi[3], WtLo[3],
                bufC16, HCp[3], HCp[3],
                AS[3], AD[3], alS, alD, C, HC);
        }
        if (l == 0) {
            gat_gather_fused<64><<<N / 4, 256, 0, stream>>>(
                bufC16, alS, alD, indptr, csr, Bc[0],
                actHi, actLo, ldoA[0], N, C, HC, HCp[0]);
        } else if (l == 1) {
            gat_gather_fused<64><<<N / 4, 256, 0, stream>>>(
                bufC16, alS, alD, indptr, csr, Bc[1],
                actHi, actLo, ldoA[1], N, C, HC, HCp[1]);
        } else if (l == 2) {
            gat_gather_fused<32><<<N / 4, 256, 0, stream>>>(
                bufC16, alS, alD, indptr, csr, Bc[2],
                actHi, actLo, ldoA[2], N, C, HC, HCp[2]);
        } else {
            gat_gather_fused<16><<<N / 4, 256, 0, stream>>>(
                bufC16, alS, alD, indptr, csr, Bc[3],
                actHi, actLo, ldoA[3], N, C, HC, HCp[3]);
        }
    }

    // ---- MLP head, fused: [8192,480(512 remapped)] -> 200 -> 100 -> 100 -> 29 ----
    mlp_fused<<<8192 / 32, 256, 0, stream>>>(
        actHi, actLo,
        LtHi[0], LtLo[0], LtHi[1], LtLo[1],
        LtHi[2], LtLo[2], LtHi[3], LtLo[3],
        LB[0], LB[1], LB[2], LB[3],
        (float*)d_out);
}